// Round 13
// baseline (161.934 us; speedup 1.0000x reference)
//
#include <hip/hip_runtime.h>
#include <cfloat>

// VQ-VAE nearest-codebook via bf16x3 split MFMA, v9 "z-in-LDS + JIT frags":
//   - z hi/lo shared in LDS (16 KB, staged once, conflict-free b128 reads)
//   - code fragments loaded JIT per s-step (2x16B) -> arch live-set ~50 regs,
//     fits the 64-arch-VGPR half of the (512,4) unified budget (R12 spilled
//     because fh/fl[4] arrays pushed arch live to ~90 vs 64 available)
//   - 4 waves/SIMD TLP hides per-step L2 latency; barrier-free main loop
//   - C-init r2n argmax epilogue (proven R10-R12)
// d_out (f32): [0,NQ) quantized | [NQ] vq_loss | [NQ+1] commitment | [NQ+2,+N) idx
// d_ws  (f32): [0,K) r2n | [K] loss | [8448...) split codebook (2 MB)

typedef __bf16 bf16x8 __attribute__((ext_vector_type(8)));
typedef float  f32x16 __attribute__((ext_vector_type(16)));

constexpr int N_ROWS = 32768;
constexpr int K_CB   = 8192;
constexpr int D_DIM  = 64;
constexpr size_t NQ  = (size_t)N_ROWS * D_DIM;
constexpr int WS_LOSS = K_CB;
constexpr size_t WS_SPLIT_F   = 8448;
constexpr size_t SPLIT_BYTES  = (size_t)K_CB * D_DIM * 4;   // 2 MB
constexpr size_t WS_NEED      = WS_SPLIT_F * 4 + SPLIT_BYTES;
constexpr int NROUND = K_CB / 256;                          // 32 rounds of 256 codes

// ---------------------------------------------------------------- prep: r2n
__global__ __launch_bounds__(256) void vq_prep(const float* __restrict__ cb,
                                               float* __restrict__ ws) {
  const int k = blockIdx.x * 256 + threadIdx.x;
  if (k == 0) ws[WS_LOSS] = 0.0f;
  const float4* p = reinterpret_cast<const float4*>(cb) + (size_t)k * 16;
  float s0 = 0.f, s1 = 0.f, s2 = 0.f, s3 = 0.f;
#pragma unroll
  for (int j = 0; j < 16; ++j) {
    float4 v = p[j];
    s0 = fmaf(v.x, v.x, s0); s1 = fmaf(v.y, v.y, s1);
    s2 = fmaf(v.z, v.z, s2); s3 = fmaf(v.w, v.w, s3);
  }
  ws[k] = -0.5f * ((s0 + s1) + (s2 + s3));   // r2n = -r2/2
}

// ------------------------------------------------- prep: split codebook in ws
// Round r (256 codes) -> 64KB block: t(=k>>5&7)*8192 + h*4096 + ch*512 + c*16.
__global__ __launch_bounds__(256) void vq_split(const float* __restrict__ cb,
                                                float* __restrict__ ws) {
  const int u  = blockIdx.x * 256 + threadIdx.x;   // 65536 threads
  const int k  = u >> 3, ch = u & 7;
  const int r  = k >> 8, t = (k >> 5) & 7, c = k & 31;
  const float* src = cb + (size_t)k * D_DIM + ch * 8;
  float4 f0 = *reinterpret_cast<const float4*>(src);
  float4 f1 = *reinterpret_cast<const float4*>(src + 4);
  float xs[8] = {f0.x, f0.y, f0.z, f0.w, f1.x, f1.y, f1.z, f1.w};
  bf16x8 hi, lo;
#pragma unroll
  for (int j = 0; j < 8; ++j) {
    __bf16 h = (__bf16)xs[j];
    hi[j] = h;
    lo[j] = (__bf16)(xs[j] - (float)h);
  }
  char* base = reinterpret_cast<char*>(ws + WS_SPLIT_F) +
               (size_t)r * 65536 + (size_t)t * 8192 + (size_t)ch * 512 + (size_t)c * 16;
  *reinterpret_cast<bf16x8*>(base)        = hi;
  *reinterpret_cast<bf16x8*>(base + 4096) = lo;
}

// ---------------------------------------------------------------- main kernel
// 512 thr = 8 waves; wave w = code-tile w (32 codes/round); 2 row-accs
// (rows rowbase + q*32 + c). z hi/lo shared in LDS. Grid 512, 4 waves/SIMD.
__global__ __launch_bounds__(512, 4) void vq_gd5(const float* __restrict__ z,
                                                 const float* __restrict__ cb,
                                                 float* __restrict__ ws,
                                                 float* __restrict__ out) {
  __shared__ __attribute__((aligned(16))) unsigned char lds[16384];
  // zh at [0,8K): slot(q,s,g,c) = q*4096 + s*1024 + g*512 + c*16 ; zl at +8K.

  const int tid = threadIdx.x;
  const int w = tid >> 6, l = tid & 63;
  const int c = l & 31, g = l >> 5;
  const int rowbase = blockIdx.x * 64;

  // ---- stage z hi/lo into LDS (once; each thread fills one 16B slot) ----
  {
    const int sc = tid & 31;
    const int sg = (tid >> 5) & 1;
    const int ss = (tid >> 6) & 3;
    const int sq = tid >> 8;
    const float* zr = z + (size_t)(rowbase + sq * 32 + sc) * D_DIM + 16 * ss + 8 * sg;
    float4 f0 = *reinterpret_cast<const float4*>(zr);
    float4 f1 = *reinterpret_cast<const float4*>(zr + 4);
    float xs[8] = {f0.x, f0.y, f0.z, f0.w, f1.x, f1.y, f1.z, f1.w};
    bf16x8 hi, lo;
#pragma unroll
    for (int j = 0; j < 8; ++j) {
      __bf16 h = (__bf16)xs[j];
      hi[j] = h;
      lo[j] = (__bf16)(xs[j] - (float)h);
    }
    const unsigned off = (unsigned)(sq * 4096 + ss * 1024 + sg * 512 + sc * 16);
    *reinterpret_cast<bf16x8*>(lds + off)        = hi;
    *reinterpret_cast<bf16x8*>(lds + 8192 + off) = lo;
  }
  __syncthreads();

  // code-fragment base pointer for my tile; hi at +s*1024, lo at +4096+s*1024
  const char* hp = reinterpret_cast<const char*>(ws + WS_SPLIT_F) +
                   (size_t)w * 8192 + (size_t)g * 512 + (size_t)c * 16;
  const float* rp = ws + w * 32 + 4 * g;

  // lane part of z LDS offsets
  const unsigned zlane = (unsigned)(g * 512 + c * 16);

  float gbest0 = -FLT_MAX, gbest1 = -FLT_MAX;
  int   bp0 = 0, bp1 = 0;   // (round<<4) | i

  for (int r = 0; r < NROUND; ++r) {
    // JIT: r2n for C-init (transient burst of 16 regs)
    float4 rv0 = *reinterpret_cast<const float4*>(rp);
    float4 rv1 = *reinterpret_cast<const float4*>(rp + 8);
    float4 rv2 = *reinterpret_cast<const float4*>(rp + 16);
    float4 rv3 = *reinterpret_cast<const float4*>(rp + 24);

    f32x16 ainit;
    ainit[0]  = rv0.x; ainit[1]  = rv0.y; ainit[2]  = rv0.z; ainit[3]  = rv0.w;
    ainit[4]  = rv1.x; ainit[5]  = rv1.y; ainit[6]  = rv1.z; ainit[7]  = rv1.w;
    ainit[8]  = rv2.x; ainit[9]  = rv2.y; ainit[10] = rv2.z; ainit[11] = rv2.w;
    ainit[12] = rv3.x; ainit[13] = rv3.y; ainit[14] = rv3.z; ainit[15] = rv3.w;
    f32x16 a0 = ainit, a1 = ainit;

    __builtin_amdgcn_s_setprio(1);
#pragma unroll
    for (int s = 0; s < 4; ++s) {
      // JIT code-fragment loads (2 x 16B from L2) right before their MFMAs
      bf16x8 fh = *reinterpret_cast<const bf16x8*>(hp + s * 1024);
      bf16x8 fl = *reinterpret_cast<const bf16x8*>(hp + 4096 + s * 1024);
      const unsigned zo = (unsigned)(s * 1024) + zlane;
      bf16x8 z0h = *reinterpret_cast<const bf16x8*>(lds + zo);
      bf16x8 z1h = *reinterpret_cast<const bf16x8*>(lds + 4096 + zo);
      bf16x8 z0l = *reinterpret_cast<const bf16x8*>(lds + 8192 + zo);
      bf16x8 z1l = *reinterpret_cast<const bf16x8*>(lds + 12288 + zo);
      a0 = __builtin_amdgcn_mfma_f32_32x32x16_bf16(fh, z0h, a0, 0, 0, 0);
      a1 = __builtin_amdgcn_mfma_f32_32x32x16_bf16(fh, z1h, a1, 0, 0, 0);
      a0 = __builtin_amdgcn_mfma_f32_32x32x16_bf16(fh, z0l, a0, 0, 0, 0);
      a1 = __builtin_amdgcn_mfma_f32_32x32x16_bf16(fh, z1l, a1, 0, 0, 0);
      a0 = __builtin_amdgcn_mfma_f32_32x32x16_bf16(fl, z0h, a0, 0, 0, 0);
      a1 = __builtin_amdgcn_mfma_f32_32x32x16_bf16(fl, z1h, a1, 0, 0, 0);
    }
    __builtin_amdgcn_s_setprio(0);

    hp += 65536;
    rp += 256;

    // epilogue: per acc, tree-max -> first-i equality scan -> global update
    const int pb = r << 4;
    {
      float m = a0[0];
#pragma unroll
      for (int i = 1; i < 16; ++i) m = fmaxf(m, a0[i]);
      int bi = 0;
#pragma unroll
      for (int i = 15; i >= 0; --i) bi = (a0[i] == m) ? i : bi;  // smallest i
      bool upd = m > gbest0;
      gbest0 = upd ? m : gbest0;
      bp0    = upd ? (pb + bi) : bp0;
    }
    {
      float m = a1[0];
#pragma unroll
      for (int i = 1; i < 16; ++i) m = fmaxf(m, a1[i]);
      int bi = 0;
#pragma unroll
      for (int i = 15; i >= 0; --i) bi = (a1[i] == m) ? i : bi;
      bool upd = m > gbest1;
      gbest1 = upd ? m : gbest1;
      bp1    = upd ? (pb + bi) : bp1;
    }
  }

  // all waves done reading z-LDS before the merge overlays it
  __syncthreads();

  // --- decode packed (round,i) -> global k, then exact-tie merges (max) ---
  int bk0, bk1;
  {
    int rr = bp0 >> 4, i = bp0 & 15;
    bk0 = rr * 256 + w * 32 + (i & 3) + 8 * (i >> 2) + 4 * g;
    rr = bp1 >> 4; i = bp1 & 15;
    bk1 = rr * 256 + w * 32 + (i & 3) + 8 * (i >> 2) + 4 * g;
  }
  // merge the two g-halves (same rows, disjoint codes)
  {
    float ob = __shfl_xor(gbest0, 32, 64);
    int   ok = __shfl_xor(bk0, 32, 64);
    if (ob > gbest0 || (ob == gbest0 && ok < bk0)) { gbest0 = ob; bk0 = ok; }
    ob = __shfl_xor(gbest1, 32, 64);
    ok = __shfl_xor(bk1, 32, 64);
    if (ob > gbest1 || (ob == gbest1 && ok < bk1)) { gbest1 = ob; bk1 = ok; }
  }

  // cross-wave merge: 8 tile-waves x 64 rows
  float* fbuf = reinterpret_cast<float*>(lds);          // [8][64]  2KB
  int*   kbuf = reinterpret_cast<int*>(lds + 2048);     // [8][64]  2KB
  int*   ibuf = reinterpret_cast<int*>(lds + 4096);     // [64]
  if (l < 32) {
    fbuf[w * 64 + c]      = gbest0;  kbuf[w * 64 + c]      = bk0;
    fbuf[w * 64 + 32 + c] = gbest1;  kbuf[w * 64 + 32 + c] = bk1;
  }
  __syncthreads();

  if (tid < 64) {
    float bb = fbuf[tid];
    int   kk = kbuf[tid];
#pragma unroll
    for (int ww = 1; ww < 8; ++ww) {
      float b2 = fbuf[ww * 64 + tid];
      int   k2 = kbuf[ww * 64 + tid];
      if (b2 > bb || (b2 == bb && k2 < kk)) { bb = b2; kk = k2; }
    }
    ibuf[tid] = kk;
    out[NQ + 2 + rowbase + tid] = (float)kk;
  }
  __syncthreads();

  // --- gather + losses: 8 threads per row (8 f32 each) ---
  {
    const int row_l = tid >> 3, seg = tid & 7;
    const int idx  = ibuf[row_l];
    const int grow = rowbase + row_l;
    const float4* qp = reinterpret_cast<const float4*>(cb + (size_t)idx * D_DIM + seg * 8);
    const float4* zp = reinterpret_cast<const float4*>(z + (size_t)grow * D_DIM + seg * 8);
    float4*       op = reinterpret_cast<float4*>(out + (size_t)grow * D_DIM + seg * 8);
    float lp = 0.f;
#pragma unroll
    for (int cc = 0; cc < 2; ++cc) {
      float4 qv = qp[cc], zv = zp[cc];
      op[cc] = qv;
      float dx = zv.x - qv.x, dy = zv.y - qv.y;
      float dz = zv.z - qv.z, dw = zv.w - qv.w;
      lp += (dx * dx + dy * dy) + (dz * dz + dw * dw);
    }
#pragma unroll
    for (int off = 32; off > 0; off >>= 1) lp += __shfl_down(lp, off, 64);
    if (l == 0) atomicAdd(ws + WS_LOSS, lp);
  }
}

// ------------------------------------------------- fallback (R4-style; adapted
// to r2n semantics: score = r2n + dot, maximize)
__global__ __launch_bounds__(512, 2) void vq_main_reg(const float* __restrict__ z,
                                                      const float* __restrict__ cb,
                                                      float* __restrict__ ws,
                                                      float* __restrict__ out) {
  __shared__ __attribute__((aligned(16))) unsigned char lds[65536];
  const int tid = threadIdx.x;
  const int w = tid >> 6, l = tid & 63;
  const int rg = w >> 1, sp = w & 1;
  const int c = l & 31, g = l >> 5;
  const int rowbase = blockIdx.x * 128;
  const int myrow = rowbase + rg * 32 + c;

  bf16x8 zh[4], zl[4];
#pragma unroll
  for (int s = 0; s < 4; ++s) {
    const float* zp = z + (size_t)myrow * D_DIM + 16 * s + 8 * g;
    float4 f0 = *reinterpret_cast<const float4*>(zp);
    float4 f1 = *reinterpret_cast<const float4*>(zp + 4);
    float xs[8] = {f0.x, f0.y, f0.z, f0.w, f1.x, f1.y, f1.z, f1.w};
#pragma unroll
    for (int j = 0; j < 8; ++j) {
      __bf16 h = (__bf16)xs[j];
      zh[s][j] = h; zl[s][j] = (__bf16)(xs[j] - (float)h);
    }
  }
  const int st_t01 = tid >> 8;
  const int st_c   = (tid >> 3) & 31;
  const int st_ch  = tid & 7;
  const unsigned st_off = (unsigned)(st_t01 * 16384 + st_ch * 512 + st_c * 16);
  const float* st_g = cb + (size_t)(st_t01 * 32 + st_c) * D_DIM + st_ch * 8;

  float best = -FLT_MAX;
  int   bidx = 0;
  float4 p0 = *reinterpret_cast<const float4*>(st_g);
  float4 p1 = *reinterpret_cast<const float4*>(st_g + 4);
  {
    float xs[8] = {p0.x, p0.y, p0.z, p0.w, p1.x, p1.y, p1.z, p1.w};
    bf16x8 hi, lo;
#pragma unroll
    for (int j = 0; j < 8; ++j) {
      __bf16 h = (__bf16)xs[j];
      hi[j] = h; lo[j] = (__bf16)(xs[j] - (float)h);
    }
    *reinterpret_cast<bf16x8*>(lds + st_off)        = hi;
    *reinterpret_cast<bf16x8*>(lds + st_off + 8192) = lo;
  }
  __syncthreads();
  const unsigned rd_base = (unsigned)(sp * 16384 + c * 16);
  for (int r = 0; r < 128; ++r) {
    const int buf = r & 1;
    if (r < 127) {
      const float* gp = st_g + (size_t)(r + 1) * (64 * D_DIM);
      p0 = *reinterpret_cast<const float4*>(gp);
      p1 = *reinterpret_cast<const float4*>(gp + 4);
    }
    const unsigned b0 = (unsigned)buf * 32768u + rd_base;
    bf16x8 ch[4], cl[4];
#pragma unroll
    for (int s = 0; s < 4; ++s) {
      unsigned off = b0 + (unsigned)((2 * s + g) * 512);
      ch[s] = *reinterpret_cast<const bf16x8*>(lds + off);
      cl[s] = *reinterpret_cast<const bf16x8*>(lds + off + 8192);
    }
    f32x16 acc;
#pragma unroll
    for (int i = 0; i < 16; ++i) acc[i] = 0.f;
#pragma unroll
    for (int s = 0; s < 4; ++s) {
      acc = __builtin_amdgcn_mfma_f32_32x32x16_bf16(ch[s], zh[s], acc, 0, 0, 0);
      acc = __builtin_amdgcn_mfma_f32_32x32x16_bf16(ch[s], zl[s], acc, 0, 0, 0);
      acc = __builtin_amdgcn_mfma_f32_32x32x16_bf16(cl[s], zh[s], acc, 0, 0, 0);
    }
    const int tb = (2 * r + sp) * 32 + 4 * g;
#pragma unroll
    for (int q = 0; q < 4; ++q) {
      float4 rv = *reinterpret_cast<const float4*>(ws + tb + 8 * q);
      float ra[4] = {rv.x, rv.y, rv.z, rv.w};
#pragma unroll
      for (int j = 0; j < 4; ++j) {
        float sc = ra[j] + acc[4 * q + j];   // r2n + dot, maximize
        int kg = tb + 8 * q + j;
        if (sc > best) { best = sc; bidx = kg; }
      }
    }
    if (r < 127) {
      float xs[8] = {p0.x, p0.y, p0.z, p0.w, p1.x, p1.y, p1.z, p1.w};
      bf16x8 hi, lo;
#pragma unroll
      for (int j = 0; j < 8; ++j) {
        __bf16 h = (__bf16)xs[j];
        hi[j] = h; lo[j] = (__bf16)(xs[j] - (float)h);
      }
      unsigned wo = (unsigned)(buf ^ 1) * 32768u + st_off;
      *reinterpret_cast<bf16x8*>(lds + wo)        = hi;
      *reinterpret_cast<bf16x8*>(lds + wo + 8192) = lo;
    }
    __syncthreads();
  }
  {
    float ob = __shfl_xor(best, 32, 64);
    int   oi = __shfl_xor(bidx, 32, 64);
    if (ob > best || (ob == best && oi < bidx)) { best = ob; bidx = oi; }
  }
  float* mf  = reinterpret_cast<float*>(lds);
  int*   mi  = reinterpret_cast<int*>(lds + 1024);
  int*   mix = reinterpret_cast<int*>(lds + 2048);
  if (l < 32) { mf[w * 32 + c] = best; mi[w * 32 + c] = bidx; }
  __syncthreads();
  if (tid < 128) {
    int rgg = tid >> 5, rl = tid & 31;
    float b0 = mf[(2 * rgg) * 32 + rl];     int i0 = mi[(2 * rgg) * 32 + rl];
    float b1 = mf[(2 * rgg + 1) * 32 + rl]; int i1 = mi[(2 * rgg + 1) * 32 + rl];
    int idx = (b1 > b0 || (b1 == b0 && i1 < i0)) ? i1 : i0;
    mix[tid] = idx;
    out[NQ + 2 + rowbase + tid] = (float)idx;
  }
  __syncthreads();
  {
    const int row_l = tid >> 2, seg = tid & 3;
    const int idx  = mix[row_l];
    const int grow = rowbase + row_l;
    const float4* qp = reinterpret_cast<const float4*>(cb + (size_t)idx * D_DIM + seg * 16);
    const float4* zp = reinterpret_cast<const float4*>(z + (size_t)grow * D_DIM + seg * 16);
    float4*       op = reinterpret_cast<float4*>(out + (size_t)grow * D_DIM + seg * 16);
    float lp = 0.f;
#pragma unroll
    for (int cc = 0; cc < 4; ++cc) {
      float4 qv = qp[cc], zv = zp[cc];
      op[cc] = qv;
      float dx = zv.x - qv.x, dy = zv.y - qv.y;
      float dz = zv.z - qv.z, dw = zv.w - qv.w;
      lp += (dx * dx + dy * dy) + (dz * dz + dw * dw);
    }
#pragma unroll
    for (int off = 32; off > 0; off >>= 1) lp += __shfl_down(lp, off, 64);
    if (l == 0) atomicAdd(ws + WS_LOSS, lp);
  }
}

// ------------------------------------------------------------ finalize kernel
__global__ void vq_fin(const float* __restrict__ ws, float* __restrict__ out) {
  float mm = ws[WS_LOSS] * (1.0f / (float)(N_ROWS * D_DIM));
  out[NQ]     = mm;
  out[NQ + 1] = mm;
}

// -------------------------------------------------------------------- launch
extern "C" void kernel_launch(void* const* d_in, const int* in_sizes, int n_in,
                              void* d_out, int out_size, void* d_ws, size_t ws_size,
                              hipStream_t stream) {
  (void)in_sizes; (void)n_in; (void)out_size;
  const float* z  = (const float*)d_in[0];
  const float* cb = (const float*)d_in[1];
  float* out = (float*)d_out;
  float* ws  = (float*)d_ws;

  vq_prep<<<K_CB / 256, 256, 0, stream>>>(cb, ws);
  if (ws_size >= WS_NEED) {
    vq_split<<<256, 256, 0, stream>>>(cb, ws);
    vq_gd5<<<N_ROWS / 64, 512, 0, stream>>>(z, cb, ws, out);
  } else {
    vq_main_reg<<<N_ROWS / 128, 512, 0, stream>>>(z, cb, ws, out);
  }
  vq_fin<<<1, 1, 0, stream>>>(ws, out);
}

// Round 14
// 155.297 us; speedup vs baseline: 1.0427x; 1.0427x over previous
//
#include <hip/hip_runtime.h>
#include <cfloat>

// VQ-VAE nearest-codebook via bf16x3 split MFMA, v10 "A/B acc double-pipeline":
//   - 4 independent MFMA chains per cluster (2 code-tiles x 2 rowsets) -> dep
//     distance 4x32 cyc covers MFMA latency (R8/R12/R13's 2-chain stall fixed)
//   - acc sets A/B alternate rounds: cluster(r+1) MFMAs overlap epilogue(r)
//     VALU within the wave (T15), all acc names static (rule #20)
//   - z hi/lo in LDS (R12-proven staging); code frags JIT per s-step from L2
//   - 64 rows/block, grid 512, 16 rounds x 512 codes; layout identical to R13
// d_out (f32): [0,NQ) quantized | [NQ] vq_loss | [NQ+1] commitment | [NQ+2,+N) idx
// d_ws  (f32): [0,K) r2n | [K] loss | [8448...) split codebook (2 MB)

typedef __bf16 bf16x8 __attribute__((ext_vector_type(8)));
typedef float  f32x16 __attribute__((ext_vector_type(16)));

constexpr int N_ROWS = 32768;
constexpr int K_CB   = 8192;
constexpr int D_DIM  = 64;
constexpr size_t NQ  = (size_t)N_ROWS * D_DIM;
constexpr int WS_LOSS = K_CB;
constexpr size_t WS_SPLIT_F   = 8448;
constexpr size_t SPLIT_BYTES  = (size_t)K_CB * D_DIM * 4;   // 2 MB
constexpr size_t WS_NEED      = WS_SPLIT_F * 4 + SPLIT_BYTES;

static __device__ __forceinline__ f32x16 MF(bf16x8 a, bf16x8 b, f32x16 c) {
  return __builtin_amdgcn_mfma_f32_32x32x16_bf16(a, b, c, 0, 0, 0);
}

// ---------------------------------------------------------------- prep: r2n
__global__ __launch_bounds__(256) void vq_prep(const float* __restrict__ cb,
                                               float* __restrict__ ws) {
  const int k = blockIdx.x * 256 + threadIdx.x;
  if (k == 0) ws[WS_LOSS] = 0.0f;
  const float4* p = reinterpret_cast<const float4*>(cb) + (size_t)k * 16;
  float s0 = 0.f, s1 = 0.f, s2 = 0.f, s3 = 0.f;
#pragma unroll
  for (int j = 0; j < 16; ++j) {
    float4 v = p[j];
    s0 = fmaf(v.x, v.x, s0); s1 = fmaf(v.y, v.y, s1);
    s2 = fmaf(v.z, v.z, s2); s3 = fmaf(v.w, v.w, s3);
  }
  ws[k] = -0.5f * ((s0 + s1) + (s2 + s3));   // r2n = -r2/2
}

// ------------------------------------------------- prep: split codebook in ws
// Linear in k: 8192B per 32-code tile; inside: h*4096 + ch*512 + c*16.
__global__ __launch_bounds__(256) void vq_split(const float* __restrict__ cb,
                                                float* __restrict__ ws) {
  const int u  = blockIdx.x * 256 + threadIdx.x;   // 65536 threads
  const int k  = u >> 3, ch = u & 7;
  const int tile = k >> 5, c = k & 31;
  const float* src = cb + (size_t)k * D_DIM + ch * 8;
  float4 f0 = *reinterpret_cast<const float4*>(src);
  float4 f1 = *reinterpret_cast<const float4*>(src + 4);
  float xs[8] = {f0.x, f0.y, f0.z, f0.w, f1.x, f1.y, f1.z, f1.w};
  bf16x8 hi, lo;
#pragma unroll
  for (int j = 0; j < 8; ++j) {
    __bf16 h = (__bf16)xs[j];
    hi[j] = h;
    lo[j] = (__bf16)(xs[j] - (float)h);
  }
  char* base = reinterpret_cast<char*>(ws + WS_SPLIT_F) +
               (size_t)tile * 8192 + (size_t)ch * 512 + (size_t)c * 16;
  *reinterpret_cast<bf16x8*>(base)        = hi;
  *reinterpret_cast<bf16x8*>(base + 4096) = lo;
}

// ---------------------------------------------------------------- main kernel
// 512 thr = 8 waves; wave w = code-tiles {2w, 2w+1} of each 512-code round;
// 2 row-accs per tile (rows rowbase + q*32 + c). 16 rounds. z in LDS.
__global__ __launch_bounds__(512, 2) void vq_ab(const float* __restrict__ z,
                                                const float* __restrict__ cb,
                                                float* __restrict__ ws,
                                                float* __restrict__ out) {
  __shared__ __attribute__((aligned(16))) unsigned char lds[16384];
  // zh at [0,8K): slot(q,s,g,c) = q*4096 + s*1024 + g*512 + c*16 ; zl at +8K.

  const int tid = threadIdx.x;
  const int w = tid >> 6, l = tid & 63;
  const int c = l & 31, g = l >> 5;
  const int rowbase = blockIdx.x * 64;

  // ---- stage z hi/lo into LDS (once; each thread fills one 16B slot) ----
  {
    const int sc = tid & 31;
    const int sg = (tid >> 5) & 1;
    const int ss = (tid >> 6) & 3;
    const int sq = tid >> 8;
    const float* zr = z + (size_t)(rowbase + sq * 32 + sc) * D_DIM + 16 * ss + 8 * sg;
    float4 f0 = *reinterpret_cast<const float4*>(zr);
    float4 f1 = *reinterpret_cast<const float4*>(zr + 4);
    float xs[8] = {f0.x, f0.y, f0.z, f0.w, f1.x, f1.y, f1.z, f1.w};
    bf16x8 hi, lo;
#pragma unroll
    for (int j = 0; j < 8; ++j) {
      __bf16 h = (__bf16)xs[j];
      hi[j] = h;
      lo[j] = (__bf16)(xs[j] - (float)h);
    }
    const unsigned off = (unsigned)(sq * 4096 + ss * 1024 + sg * 512 + sc * 16);
    *reinterpret_cast<bf16x8*>(lds + off)        = hi;
    *reinterpret_cast<bf16x8*>(lds + 8192 + off) = lo;
  }
  __syncthreads();

  const char* cbbase = reinterpret_cast<const char*>(ws + WS_SPLIT_F) +
                       (size_t)w * 16384 + (size_t)g * 512 + (size_t)c * 16;
  const unsigned zlane = (unsigned)(g * 512 + c * 16);

  float gbest0 = -FLT_MAX, gbest1 = -FLT_MAX;
  int   bp0 = 0, bp1 = 0;   // (round<<5) | (tt<<4) | i

// cluster: C-init from r2n, then 4 s-steps x 12 MFMA (4 chains, dist 4)
#define CLUSTER(A00, A01, A10, A11, RR)                                        \
  do {                                                                         \
    const int rr_ = (RR);                                                      \
    const float* rp_ = ws + rr_ * 512 + w * 64 + 4 * g;                        \
    float4 p0 = *reinterpret_cast<const float4*>(rp_);                         \
    float4 p1 = *reinterpret_cast<const float4*>(rp_ + 8);                     \
    float4 p2 = *reinterpret_cast<const float4*>(rp_ + 16);                    \
    float4 p3 = *reinterpret_cast<const float4*>(rp_ + 24);                    \
    float4 p4 = *reinterpret_cast<const float4*>(rp_ + 32);                    \
    float4 p5 = *reinterpret_cast<const float4*>(rp_ + 40);                    \
    float4 p6 = *reinterpret_cast<const float4*>(rp_ + 48);                    \
    float4 p7 = *reinterpret_cast<const float4*>(rp_ + 56);                    \
    f32x16 i0, i1;                                                             \
    i0[0] = p0.x; i0[1] = p0.y; i0[2]  = p0.z; i0[3]  = p0.w;                  \
    i0[4] = p1.x; i0[5] = p1.y; i0[6]  = p1.z; i0[7]  = p1.w;                  \
    i0[8] = p2.x; i0[9] = p2.y; i0[10] = p2.z; i0[11] = p2.w;                  \
    i0[12] = p3.x; i0[13] = p3.y; i0[14] = p3.z; i0[15] = p3.w;                \
    i1[0] = p4.x; i1[1] = p4.y; i1[2]  = p4.z; i1[3]  = p4.w;                  \
    i1[4] = p5.x; i1[5] = p5.y; i1[6]  = p5.z; i1[7]  = p5.w;                  \
    i1[8] = p6.x; i1[9] = p6.y; i1[10] = p6.z; i1[11] = p6.w;                  \
    i1[12] = p7.x; i1[13] = p7.y; i1[14] = p7.z; i1[15] = p7.w;                \
    A00 = i0; A01 = i0; A10 = i1; A11 = i1;                                    \
    const char* cb_ = cbbase + (size_t)rr_ * 131072;                           \
    _Pragma("unroll")                                                          \
    for (int s = 0; s < 4; ++s) {                                              \
      bf16x8 fh0 = *reinterpret_cast<const bf16x8*>(cb_ + s * 1024);           \
      bf16x8 fl0 = *reinterpret_cast<const bf16x8*>(cb_ + 4096 + s * 1024);    \
      bf16x8 fh1 = *reinterpret_cast<const bf16x8*>(cb_ + 8192 + s * 1024);    \
      bf16x8 fl1 = *reinterpret_cast<const bf16x8*>(cb_ + 12288 + s * 1024);   \
      const unsigned zo = (unsigned)(s * 1024) + zlane;                        \
      bf16x8 z0h = *reinterpret_cast<const bf16x8*>(lds + zo);                 \
      bf16x8 z1h = *reinterpret_cast<const bf16x8*>(lds + 4096 + zo);          \
      bf16x8 z0l = *reinterpret_cast<const bf16x8*>(lds + 8192 + zo);          \
      bf16x8 z1l = *reinterpret_cast<const bf16x8*>(lds + 12288 + zo);         \
      A00 = MF(fh0, z0h, A00); A01 = MF(fh0, z1h, A01);                        \
      A10 = MF(fh1, z0h, A10); A11 = MF(fh1, z1h, A11);                        \
      A00 = MF(fh0, z0l, A00); A01 = MF(fh0, z1l, A01);                        \
      A10 = MF(fh1, z0l, A10); A11 = MF(fh1, z1l, A11);                        \
      A00 = MF(fl0, z0h, A00); A01 = MF(fl0, z1h, A01);                        \
      A10 = MF(fl1, z0h, A10); A11 = MF(fl1, z1h, A11);                        \
    }                                                                          \
  } while (0)

// epilogue: tree-max + first-i scan per acc; tt=0 before tt=1, strict '>'
#define EPI1(ACC, GB, BP, PB)                                                  \
  do {                                                                         \
    float m_ = ACC[0];                                                         \
    _Pragma("unroll")                                                          \
    for (int i = 1; i < 16; ++i) m_ = fmaxf(m_, ACC[i]);                       \
    int bi_ = 0;                                                               \
    _Pragma("unroll")                                                          \
    for (int i = 15; i >= 0; --i) bi_ = (ACC[i] == m_) ? i : bi_;              \
    if (m_ > GB) { GB = m_; BP = (PB) + bi_; }                                 \
  } while (0)

#define EPI(A00, A01, A10, A11, RR)                                            \
  do {                                                                         \
    const int pb0_ = ((RR) << 5);                                              \
    const int pb1_ = ((RR) << 5) | 16;                                         \
    EPI1(A00, gbest0, bp0, pb0_);                                              \
    EPI1(A10, gbest0, bp0, pb1_);                                              \
    EPI1(A01, gbest1, bp1, pb0_);                                              \
    EPI1(A11, gbest1, bp1, pb1_);                                              \
  } while (0)

  f32x16 aA00, aA01, aA10, aA11, aB00, aB01, aB10, aB11;

  CLUSTER(aA00, aA01, aA10, aA11, 0);
  CLUSTER(aB00, aB01, aB10, aB11, 1);
  EPI(aA00, aA01, aA10, aA11, 0);
  for (int t = 1; t < 8; ++t) {
    CLUSTER(aA00, aA01, aA10, aA11, 2 * t);
    EPI(aB00, aB01, aB10, aB11, 2 * t - 1);
    CLUSTER(aB00, aB01, aB10, aB11, 2 * t + 1);
    EPI(aA00, aA01, aA10, aA11, 2 * t);
  }
  EPI(aB00, aB01, aB10, aB11, 15);

#undef CLUSTER
#undef EPI1
#undef EPI

  // all waves done reading z-LDS before the merge overlays it
  __syncthreads();

  // --- decode packed (round,tt,i) -> global k, then exact-tie merges (max) ---
  int bk0, bk1;
  {
    int rr = bp0 >> 5, tt = (bp0 >> 4) & 1, i = bp0 & 15;
    bk0 = rr * 512 + w * 64 + tt * 32 + (i & 3) + 8 * (i >> 2) + 4 * g;
    rr = bp1 >> 5; tt = (bp1 >> 4) & 1; i = bp1 & 15;
    bk1 = rr * 512 + w * 64 + tt * 32 + (i & 3) + 8 * (i >> 2) + 4 * g;
  }
  // merge the two g-halves (same rows, disjoint codes)
  {
    float ob = __shfl_xor(gbest0, 32, 64);
    int   ok = __shfl_xor(bk0, 32, 64);
    if (ob > gbest0 || (ob == gbest0 && ok < bk0)) { gbest0 = ob; bk0 = ok; }
    ob = __shfl_xor(gbest1, 32, 64);
    ok = __shfl_xor(bk1, 32, 64);
    if (ob > gbest1 || (ob == gbest1 && ok < bk1)) { gbest1 = ob; bk1 = ok; }
  }

  // cross-wave merge: 8 waves x 64 rows
  float* fbuf = reinterpret_cast<float*>(lds);          // [8][64]  2KB
  int*   kbuf = reinterpret_cast<int*>(lds + 2048);     // [8][64]  2KB
  int*   ibuf = reinterpret_cast<int*>(lds + 4096);     // [64]
  if (l < 32) {
    fbuf[w * 64 + c]      = gbest0;  kbuf[w * 64 + c]      = bk0;
    fbuf[w * 64 + 32 + c] = gbest1;  kbuf[w * 64 + 32 + c] = bk1;
  }
  __syncthreads();

  if (tid < 64) {
    float bb = fbuf[tid];
    int   kk = kbuf[tid];
#pragma unroll
    for (int ww = 1; ww < 8; ++ww) {
      float b2 = fbuf[ww * 64 + tid];
      int   k2 = kbuf[ww * 64 + tid];
      if (b2 > bb || (b2 == bb && k2 < kk)) { bb = b2; kk = k2; }
    }
    ibuf[tid] = kk;
    out[NQ + 2 + rowbase + tid] = (float)kk;
  }
  __syncthreads();

  // --- gather + losses: 8 threads per row (8 f32 each) ---
  {
    const int row_l = tid >> 3, seg = tid & 7;
    const int idx  = ibuf[row_l];
    const int grow = rowbase + row_l;
    const float4* qp = reinterpret_cast<const float4*>(cb + (size_t)idx * D_DIM + seg * 8);
    const float4* zp = reinterpret_cast<const float4*>(z + (size_t)grow * D_DIM + seg * 8);
    float4*       op = reinterpret_cast<float4*>(out + (size_t)grow * D_DIM + seg * 8);
    float lp = 0.f;
#pragma unroll
    for (int cc = 0; cc < 2; ++cc) {
      float4 qv = qp[cc], zv = zp[cc];
      op[cc] = qv;
      float dx = zv.x - qv.x, dy = zv.y - qv.y;
      float dz = zv.z - qv.z, dw = zv.w - qv.w;
      lp += (dx * dx + dy * dy) + (dz * dz + dw * dw);
    }
#pragma unroll
    for (int off = 32; off > 0; off >>= 1) lp += __shfl_down(lp, off, 64);
    if (l == 0) atomicAdd(ws + WS_LOSS, lp);
  }
}

// ------------------------------------------------- fallback (R4-style; adapted
// to r2n semantics: score = r2n + dot, maximize)
__global__ __launch_bounds__(512, 2) void vq_main_reg(const float* __restrict__ z,
                                                      const float* __restrict__ cb,
                                                      float* __restrict__ ws,
                                                      float* __restrict__ out) {
  __shared__ __attribute__((aligned(16))) unsigned char lds[65536];
  const int tid = threadIdx.x;
  const int w = tid >> 6, l = tid & 63;
  const int rg = w >> 1, sp = w & 1;
  const int c = l & 31, g = l >> 5;
  const int rowbase = blockIdx.x * 128;
  const int myrow = rowbase + rg * 32 + c;

  bf16x8 zh[4], zl[4];
#pragma unroll
  for (int s = 0; s < 4; ++s) {
    const float* zp = z + (size_t)myrow * D_DIM + 16 * s + 8 * g;
    float4 f0 = *reinterpret_cast<const float4*>(zp);
    float4 f1 = *reinterpret_cast<const float4*>(zp + 4);
    float xs[8] = {f0.x, f0.y, f0.z, f0.w, f1.x, f1.y, f1.z, f1.w};
#pragma unroll
    for (int j = 0; j < 8; ++j) {
      __bf16 h = (__bf16)xs[j];
      zh[s][j] = h; zl[s][j] = (__bf16)(xs[j] - (float)h);
    }
  }
  const int st_t01 = tid >> 8;
  const int st_c   = (tid >> 3) & 31;
  const int st_ch  = tid & 7;
  const unsigned st_off = (unsigned)(st_t01 * 16384 + st_ch * 512 + st_c * 16);
  const float* st_g = cb + (size_t)(st_t01 * 32 + st_c) * D_DIM + st_ch * 8;

  float best = -FLT_MAX;
  int   bidx = 0;
  float4 p0 = *reinterpret_cast<const float4*>(st_g);
  float4 p1 = *reinterpret_cast<const float4*>(st_g + 4);
  {
    float xs[8] = {p0.x, p0.y, p0.z, p0.w, p1.x, p1.y, p1.z, p1.w};
    bf16x8 hi, lo;
#pragma unroll
    for (int j = 0; j < 8; ++j) {
      __bf16 h = (__bf16)xs[j];
      hi[j] = h; lo[j] = (__bf16)(xs[j] - (float)h);
    }
    *reinterpret_cast<bf16x8*>(lds + st_off)        = hi;
    *reinterpret_cast<bf16x8*>(lds + st_off + 8192) = lo;
  }
  __syncthreads();
  const unsigned rd_base = (unsigned)(sp * 16384 + c * 16);
  for (int r = 0; r < 128; ++r) {
    const int buf = r & 1;
    if (r < 127) {
      const float* gp = st_g + (size_t)(r + 1) * (64 * D_DIM);
      p0 = *reinterpret_cast<const float4*>(gp);
      p1 = *reinterpret_cast<const float4*>(gp + 4);
    }
    const unsigned b0 = (unsigned)buf * 32768u + rd_base;
    bf16x8 ch[4], cl[4];
#pragma unroll
    for (int s = 0; s < 4; ++s) {
      unsigned off = b0 + (unsigned)((2 * s + g) * 512);
      ch[s] = *reinterpret_cast<const bf16x8*>(lds + off);
      cl[s] = *reinterpret_cast<const bf16x8*>(lds + off + 8192);
    }
    f32x16 acc;
#pragma unroll
    for (int i = 0; i < 16; ++i) acc[i] = 0.f;
#pragma unroll
    for (int s = 0; s < 4; ++s) {
      acc = __builtin_amdgcn_mfma_f32_32x32x16_bf16(ch[s], zh[s], acc, 0, 0, 0);
      acc = __builtin_amdgcn_mfma_f32_32x32x16_bf16(ch[s], zl[s], acc, 0, 0, 0);
      acc = __builtin_amdgcn_mfma_f32_32x32x16_bf16(cl[s], zh[s], acc, 0, 0, 0);
    }
    const int tb = (2 * r + sp) * 32 + 4 * g;
#pragma unroll
    for (int q = 0; q < 4; ++q) {
      float4 rv = *reinterpret_cast<const float4*>(ws + tb + 8 * q);
      float ra[4] = {rv.x, rv.y, rv.z, rv.w};
#pragma unroll
      for (int j = 0; j < 4; ++j) {
        float sc = ra[j] + acc[4 * q + j];   // r2n + dot, maximize
        int kg = tb + 8 * q + j;
        if (sc > best) { best = sc; bidx = kg; }
      }
    }
    if (r < 127) {
      float xs[8] = {p0.x, p0.y, p0.z, p0.w, p1.x, p1.y, p1.z, p1.w};
      bf16x8 hi, lo;
#pragma unroll
      for (int j = 0; j < 8; ++j) {
        __bf16 h = (__bf16)xs[j];
        hi[j] = h; lo[j] = (__bf16)(xs[j] - (float)h);
      }
      unsigned wo = (unsigned)(buf ^ 1) * 32768u + st_off;
      *reinterpret_cast<bf16x8*>(lds + wo)        = hi;
      *reinterpret_cast<bf16x8*>(lds + wo + 8192) = lo;
    }
    __syncthreads();
  }
  {
    float ob = __shfl_xor(best, 32, 64);
    int   oi = __shfl_xor(bidx, 32, 64);
    if (ob > best || (ob == best && oi < bidx)) { best = ob; bidx = oi; }
  }
  float* mf  = reinterpret_cast<float*>(lds);
  int*   mi  = reinterpret_cast<int*>(lds + 1024);
  int*   mix = reinterpret_cast<int*>(lds + 2048);
  if (l < 32) { mf[w * 32 + c] = best; mi[w * 32 + c] = bidx; }
  __syncthreads();
  if (tid < 128) {
    int rgg = tid >> 5, rl = tid & 31;
    float b0 = mf[(2 * rgg) * 32 + rl];     int i0 = mi[(2 * rgg) * 32 + rl];
    float b1 = mf[(2 * rgg + 1) * 32 + rl]; int i1 = mi[(2 * rgg + 1) * 32 + rl];
    int idx = (b1 > b0 || (b1 == b0 && i1 < i0)) ? i1 : i0;
    mix[tid] = idx;
    out[NQ + 2 + rowbase + tid] = (float)idx;
  }
  __syncthreads();
  {
    const int row_l = tid >> 2, seg = tid & 3;
    const int idx  = mix[row_l];
    const int grow = rowbase + row_l;
    const float4* qp = reinterpret_cast<const float4*>(cb + (size_t)idx * D_DIM + seg * 16);
    const float4* zp = reinterpret_cast<const float4*>(z + (size_t)grow * D_DIM + seg * 16);
    float4*       op = reinterpret_cast<float4*>(out + (size_t)grow * D_DIM + seg * 16);
    float lp = 0.f;
#pragma unroll
    for (int cc = 0; cc < 4; ++cc) {
      float4 qv = qp[cc], zv = zp[cc];
      op[cc] = qv;
      float dx = zv.x - qv.x, dy = zv.y - qv.y;
      float dz = zv.z - qv.z, dw = zv.w - qv.w;
      lp += (dx * dx + dy * dy) + (dz * dz + dw * dw);
    }
#pragma unroll
    for (int off = 32; off > 0; off >>= 1) lp += __shfl_down(lp, off, 64);
    if (l == 0) atomicAdd(ws + WS_LOSS, lp);
  }
}

// ------------------------------------------------------------ finalize kernel
__global__ void vq_fin(const float* __restrict__ ws, float* __restrict__ out) {
  float mm = ws[WS_LOSS] * (1.0f / (float)(N_ROWS * D_DIM));
  out[NQ]     = mm;
  out[NQ + 1] = mm;
}

// -------------------------------------------------------------------- launch
extern "C" void kernel_launch(void* const* d_in, const int* in_sizes, int n_in,
                              void* d_out, int out_size, void* d_ws, size_t ws_size,
                              hipStream_t stream) {
  (void)in_sizes; (void)n_in; (void)out_size;
  const float* z  = (const float*)d_in[0];
  const float* cb = (const float*)d_in[1];
  float* out = (float*)d_out;
  float* ws  = (float*)d_ws;

  vq_prep<<<K_CB / 256, 256, 0, stream>>>(cb, ws);
  if (ws_size >= WS_NEED) {
    vq_split<<<256, 256, 0, stream>>>(cb, ws);
    vq_ab<<<N_ROWS / 64, 512, 0, stream>>>(z, cb, ws, out);
  } else {
    vq_main_reg<<<N_ROWS / 128, 512, 0, stream>>>(z, cb, ws, out);
  }
  vq_fin<<<1, 1, 0, stream>>>(ws, out);
}

// Round 15
// 153.990 us; speedup vs baseline: 1.0516x; 1.0085x over previous
//
#include <hip/hip_runtime.h>
#include <cfloat>

// VQ-VAE nearest-codebook via bf16x3 split MFMA, v11 "R10 + hazard fixes":
//   - R10 structure (4 chains, 128 rows/block, grid 256, barrier-free)
//   - double-buffered fragment sets: loads for r+1 issue at TOP of round r
//     (R10 reloaded same regs -> WAR blocked issue until cluster done)
//   - acc re-init fused into epilogue (distance between accvgpr_write and
//     first MFMA read = other accs' epilogues, not zero)
//   - no s_setprio (m190: negative on pre-8-phase GEMM)
// d_out (f32): [0,NQ) quantized | [NQ] vq_loss | [NQ+1] commitment | [NQ+2,+N) idx
// d_ws  (f32): [0,K) r2n | [K] loss | [8448...) split codebook (2 MB)

typedef __bf16 bf16x8 __attribute__((ext_vector_type(8)));
typedef float  f32x16 __attribute__((ext_vector_type(16)));

constexpr int N_ROWS = 32768;
constexpr int K_CB   = 8192;
constexpr int D_DIM  = 64;
constexpr size_t NQ  = (size_t)N_ROWS * D_DIM;
constexpr int WS_LOSS = K_CB;
constexpr size_t WS_SPLIT_F   = 8448;
constexpr size_t SPLIT_BYTES  = (size_t)K_CB * D_DIM * 4;   // 2 MB
constexpr size_t WS_NEED      = WS_SPLIT_F * 4 + SPLIT_BYTES;

static __device__ __forceinline__ f32x16 MF(bf16x8 a, bf16x8 b, f32x16 c) {
  return __builtin_amdgcn_mfma_f32_32x32x16_bf16(a, b, c, 0, 0, 0);
}

// ---------------------------------------------------------------- prep: r2n
__global__ __launch_bounds__(256) void vq_prep(const float* __restrict__ cb,
                                               float* __restrict__ ws) {
  const int k = blockIdx.x * 256 + threadIdx.x;
  if (k == 0) ws[WS_LOSS] = 0.0f;
  const float4* p = reinterpret_cast<const float4*>(cb) + (size_t)k * 16;
  float s0 = 0.f, s1 = 0.f, s2 = 0.f, s3 = 0.f;
#pragma unroll
  for (int j = 0; j < 16; ++j) {
    float4 v = p[j];
    s0 = fmaf(v.x, v.x, s0); s1 = fmaf(v.y, v.y, s1);
    s2 = fmaf(v.z, v.z, s2); s3 = fmaf(v.w, v.w, s3);
  }
  ws[k] = -0.5f * ((s0 + s1) + (s2 + s3));   // r2n = -r2/2
}

// ------------------------------------------------- prep: split codebook in ws
// Round r (256 codes) -> 64KB block: t(=k>>5&7)*8192 + h*4096 + ch*512 + c*16.
__global__ __launch_bounds__(256) void vq_split(const float* __restrict__ cb,
                                                float* __restrict__ ws) {
  const int u  = blockIdx.x * 256 + threadIdx.x;   // 65536 threads
  const int k  = u >> 3, ch = u & 7;
  const int r  = k >> 8, t = (k >> 5) & 7, c = k & 31;
  const float* src = cb + (size_t)k * D_DIM + ch * 8;
  float4 f0 = *reinterpret_cast<const float4*>(src);
  float4 f1 = *reinterpret_cast<const float4*>(src + 4);
  float xs[8] = {f0.x, f0.y, f0.z, f0.w, f1.x, f1.y, f1.z, f1.w};
  bf16x8 hi, lo;
#pragma unroll
  for (int j = 0; j < 8; ++j) {
    __bf16 h = (__bf16)xs[j];
    hi[j] = h;
    lo[j] = (__bf16)(xs[j] - (float)h);
  }
  char* base = reinterpret_cast<char*>(ws + WS_SPLIT_F) +
               (size_t)r * 65536 + (size_t)t * 8192 + (size_t)ch * 512 + (size_t)c * 16;
  *reinterpret_cast<bf16x8*>(base)        = hi;
  *reinterpret_cast<bf16x8*>(base + 4096) = lo;
}

// ---------------------------------------------------------------- main kernel
__global__ __launch_bounds__(512, 2) void vq_gd6(const float* __restrict__ z,
                                                 const float* __restrict__ cb,
                                                 float* __restrict__ ws,
                                                 float* __restrict__ out) {
  __shared__ __attribute__((aligned(16))) unsigned char lds[12288];

  const int tid = threadIdx.x;
  const int w = tid >> 6, l = tid & 63;
  const int c = l & 31, g = l >> 5;
  const int rowbase = blockIdx.x * 128;

  // --- z fragments: 4 rowsets x 4 k-steps, hi/lo split, registers forever ---
  bf16x8 zh[4][4], zl[4][4];
#pragma unroll
  for (int q = 0; q < 4; ++q) {
    const float* zr = z + (size_t)(rowbase + q * 32 + c) * D_DIM + 8 * g;
#pragma unroll
    for (int s = 0; s < 4; ++s) {
      float4 f0 = *reinterpret_cast<const float4*>(zr + 16 * s);
      float4 f1 = *reinterpret_cast<const float4*>(zr + 16 * s + 4);
      float xs[8] = {f0.x, f0.y, f0.z, f0.w, f1.x, f1.y, f1.z, f1.w};
#pragma unroll
      for (int j = 0; j < 8; ++j) {
        __bf16 h = (__bf16)xs[j];
        zh[q][s][j] = h;
        zl[q][s][j] = (__bf16)(xs[j] - (float)h);
      }
    }
  }

  const char*  cbbase = reinterpret_cast<const char*>(ws + WS_SPLIT_F) +
                        (size_t)w * 8192 + (size_t)g * 512 + (size_t)c * 16;
  const float* rbase  = ws + w * 32 + 4 * g;

#define LOADF(FH, FL, RIDX)                                                    \
  do {                                                                         \
    const char* p_ = cbbase + (size_t)(RIDX) * 65536;                          \
    _Pragma("unroll")                                                          \
    for (int s = 0; s < 4; ++s) {                                              \
      FH[s] = *reinterpret_cast<const bf16x8*>(p_ + s * 1024);                 \
      FL[s] = *reinterpret_cast<const bf16x8*>(p_ + 4096 + s * 1024);          \
    }                                                                          \
  } while (0)

#define LOADRV(RIDX)                                                           \
  do {                                                                         \
    const float* q_ = rbase + (RIDX) * 256;                                    \
    rv0 = *reinterpret_cast<const float4*>(q_);                                \
    rv1 = *reinterpret_cast<const float4*>(q_ + 8);                            \
    rv2 = *reinterpret_cast<const float4*>(q_ + 16);                           \
    rv3 = *reinterpret_cast<const float4*>(q_ + 24);                           \
  } while (0)

#define MKINIT(DST)                                                            \
  do {                                                                         \
    DST[0]  = rv0.x; DST[1]  = rv0.y; DST[2]  = rv0.z; DST[3]  = rv0.w;        \
    DST[4]  = rv1.x; DST[5]  = rv1.y; DST[6]  = rv1.z; DST[7]  = rv1.w;        \
    DST[8]  = rv2.x; DST[9]  = rv2.y; DST[10] = rv2.z; DST[11] = rv2.w;        \
    DST[12] = rv3.x; DST[13] = rv3.y; DST[14] = rv3.z; DST[15] = rv3.w;        \
  } while (0)

#define CLUSTER(FH, FL)                                                        \
  do {                                                                         \
    _Pragma("unroll")                                                          \
    for (int s = 0; s < 4; ++s) {                                              \
      a0 = MF(FH[s], zh[0][s], a0); a1 = MF(FH[s], zh[1][s], a1);              \
      a2 = MF(FH[s], zh[2][s], a2); a3 = MF(FH[s], zh[3][s], a3);              \
      a0 = MF(FH[s], zl[0][s], a0); a1 = MF(FH[s], zl[1][s], a1);              \
      a2 = MF(FH[s], zl[2][s], a2); a3 = MF(FH[s], zl[3][s], a3);              \
      a0 = MF(FL[s], zh[0][s], a0); a1 = MF(FL[s], zh[1][s], a1);              \
      a2 = MF(FL[s], zh[2][s], a2); a3 = MF(FL[s], zh[3][s], a3);              \
    }                                                                          \
  } while (0)

// epilogue for one acc: tree-max, first-i scan, conditional update, re-init
#define EPI1(ACC, GB, BP, PB)                                                  \
  do {                                                                         \
    float m_ = ACC[0];                                                         \
    _Pragma("unroll")                                                          \
    for (int i = 1; i < 16; ++i) m_ = fmaxf(m_, ACC[i]);                       \
    int bi_ = 0;                                                               \
    _Pragma("unroll")                                                          \
    for (int i = 15; i >= 0; --i) bi_ = (ACC[i] == m_) ? i : bi_;              \
    if (m_ > GB) { GB = m_; BP = (PB) + bi_; }                                 \
    ACC = inx;                                                                 \
  } while (0)

#define EPI4(RR)                                                               \
  do {                                                                         \
    f32x16 inx;                                                                \
    MKINIT(inx);                                                               \
    const int pb_ = (RR) << 4;                                                 \
    EPI1(a0, gbest[0], bpack[0], pb_);                                         \
    EPI1(a1, gbest[1], bpack[1], pb_);                                         \
    EPI1(a2, gbest[2], bpack[2], pb_);                                         \
    EPI1(a3, gbest[3], bpack[3], pb_);                                         \
  } while (0)

  bf16x8 fhA[4], flA[4], fhB[4], flB[4];
  float4 rv0, rv1, rv2, rv3;
  f32x16 a0, a1, a2, a3;

  float gbest[4];
  int   bpack[4];
#pragma unroll
  for (int q = 0; q < 4; ++q) { gbest[q] = -FLT_MAX; bpack[q] = 0; }

  // prologue: round 0 fragments + rv(0) -> init accs
  LOADF(fhA, flA, 0);
  LOADRV(0);
  {
    f32x16 i0;
    MKINIT(i0);
    a0 = i0; a1 = i0; a2 = i0; a3 = i0;
  }

  for (int t = 0; t < 16; ++t) {
    const int r0 = 2 * t, r1 = 2 * t + 1;
    // even round r0: prefetch r1 into B, rv(r1) for re-init
    LOADF(fhB, flB, r1);
    LOADRV(r1);
    CLUSTER(fhA, flA);
    EPI4(r0);                       // update + re-init accs from rv(r1)
    // odd round r1: prefetch next even round into A (clamped), rv likewise
    const int r2 = (r1 < 31) ? r1 + 1 : 31;
    LOADF(fhA, flA, r2);
    LOADRV(r2);
    CLUSTER(fhB, flB);
    EPI4(r1);                       // update + re-init accs from rv(r2)
  }

#undef LOADF
#undef LOADRV
#undef MKINIT
#undef CLUSTER
#undef EPI1
#undef EPI4

  // --- decode packed (round,i) -> global k, then exact-tie merges (max) ---
  int bk[4];
#pragma unroll
  for (int q = 0; q < 4; ++q) {
    int rr = bpack[q] >> 4, i = bpack[q] & 15;
    int cid = (i & 3) + 8 * (i >> 2) + 4 * g;
    bk[q] = rr * 256 + w * 32 + cid;
  }
#pragma unroll
  for (int q = 0; q < 4; ++q) {
    float ob = __shfl_xor(gbest[q], 32, 64);
    int   ok = __shfl_xor(bk[q], 32, 64);
    if (ob > gbest[q] || (ob == gbest[q] && ok < bk[q])) { gbest[q] = ob; bk[q] = ok; }
  }

  float* fbuf = reinterpret_cast<float*>(lds);          // [8 tiles][128 rows]
  int*   kbuf = reinterpret_cast<int*>(lds + 4096);     // [8][128]
  int*   ibuf = reinterpret_cast<int*>(lds + 8192);     // [128]
  if (l < 32) {
#pragma unroll
    for (int q = 0; q < 4; ++q) {
      fbuf[w * 128 + q * 32 + l] = gbest[q];
      kbuf[w * 128 + q * 32 + l] = bk[q];
    }
  }
  __syncthreads();

  if (tid < 128) {
    float bb = fbuf[tid];
    int   kk = kbuf[tid];
#pragma unroll
    for (int ww = 1; ww < 8; ++ww) {
      float b2 = fbuf[ww * 128 + tid];
      int   k2 = kbuf[ww * 128 + tid];
      if (b2 > bb || (b2 == bb && k2 < kk)) { bb = b2; kk = k2; }
    }
    ibuf[tid] = kk;
    out[NQ + 2 + rowbase + tid] = (float)kk;
  }
  __syncthreads();

  // --- gather + losses: 4 threads per row ---
  {
    const int row_l = tid >> 2, seg = tid & 3;
    const int idx  = ibuf[row_l];
    const int grow = rowbase + row_l;
    const float4* qp = reinterpret_cast<const float4*>(cb + (size_t)idx * D_DIM + seg * 16);
    const float4* zp = reinterpret_cast<const float4*>(z + (size_t)grow * D_DIM + seg * 16);
    float4*       op = reinterpret_cast<float4*>(out + (size_t)grow * D_DIM + seg * 16);
    float lp = 0.f;
#pragma unroll
    for (int cc = 0; cc < 4; ++cc) {
      float4 qv = qp[cc], zv = zp[cc];
      op[cc] = qv;
      float dx = zv.x - qv.x, dy = zv.y - qv.y;
      float dz = zv.z - qv.z, dw = zv.w - qv.w;
      lp += (dx * dx + dy * dy) + (dz * dz + dw * dw);
    }
#pragma unroll
    for (int off = 32; off > 0; off >>= 1) lp += __shfl_down(lp, off, 64);
    if (l == 0) atomicAdd(ws + WS_LOSS, lp);
  }
}

// ------------------------------------------------- fallback (R4-style; adapted
// to r2n semantics: score = r2n + dot, maximize)
__global__ __launch_bounds__(512, 2) void vq_main_reg(const float* __restrict__ z,
                                                      const float* __restrict__ cb,
                                                      float* __restrict__ ws,
                                                      float* __restrict__ out) {
  __shared__ __attribute__((aligned(16))) unsigned char lds[65536];
  const int tid = threadIdx.x;
  const int w = tid >> 6, l = tid & 63;
  const int rg = w >> 1, sp = w & 1;
  const int c = l & 31, g = l >> 5;
  const int rowbase = blockIdx.x * 128;
  const int myrow = rowbase + rg * 32 + c;

  bf16x8 zh[4], zl[4];
#pragma unroll
  for (int s = 0; s < 4; ++s) {
    const float* zp = z + (size_t)myrow * D_DIM + 16 * s + 8 * g;
    float4 f0 = *reinterpret_cast<const float4*>(zp);
    float4 f1 = *reinterpret_cast<const float4*>(zp + 4);
    float xs[8] = {f0.x, f0.y, f0.z, f0.w, f1.x, f1.y, f1.z, f1.w};
#pragma unroll
    for (int j = 0; j < 8; ++j) {
      __bf16 h = (__bf16)xs[j];
      zh[s][j] = h; zl[s][j] = (__bf16)(xs[j] - (float)h);
    }
  }
  const int st_t01 = tid >> 8;
  const int st_c   = (tid >> 3) & 31;
  const int st_ch  = tid & 7;
  const unsigned st_off = (unsigned)(st_t01 * 16384 + st_ch * 512 + st_c * 16);
  const float* st_g = cb + (size_t)(st_t01 * 32 + st_c) * D_DIM + st_ch * 8;

  float best = -FLT_MAX;
  int   bidx = 0;
  float4 p0 = *reinterpret_cast<const float4*>(st_g);
  float4 p1 = *reinterpret_cast<const float4*>(st_g + 4);
  {
    float xs[8] = {p0.x, p0.y, p0.z, p0.w, p1.x, p1.y, p1.z, p1.w};
    bf16x8 hi, lo;
#pragma unroll
    for (int j = 0; j < 8; ++j) {
      __bf16 h = (__bf16)xs[j];
      hi[j] = h; lo[j] = (__bf16)(xs[j] - (float)h);
    }
    *reinterpret_cast<bf16x8*>(lds + st_off)        = hi;
    *reinterpret_cast<bf16x8*>(lds + st_off + 8192) = lo;
  }
  __syncthreads();
  const unsigned rd_base = (unsigned)(sp * 16384 + c * 16);
  for (int r = 0; r < 128; ++r) {
    const int buf = r & 1;
    if (r < 127) {
      const float* gp = st_g + (size_t)(r + 1) * (64 * D_DIM);
      p0 = *reinterpret_cast<const float4*>(gp);
      p1 = *reinterpret_cast<const float4*>(gp + 4);
    }
    const unsigned b0 = (unsigned)buf * 32768u + rd_base;
    bf16x8 ch[4], cl[4];
#pragma unroll
    for (int s = 0; s < 4; ++s) {
      unsigned off = b0 + (unsigned)((2 * s + g) * 512);
      ch[s] = *reinterpret_cast<const bf16x8*>(lds + off);
      cl[s] = *reinterpret_cast<const bf16x8*>(lds + off + 8192);
    }
    f32x16 acc;
#pragma unroll
    for (int i = 0; i < 16; ++i) acc[i] = 0.f;
#pragma unroll
    for (int s = 0; s < 4; ++s) {
      acc = __builtin_amdgcn_mfma_f32_32x32x16_bf16(ch[s], zh[s], acc, 0, 0, 0);
      acc = __builtin_amdgcn_mfma_f32_32x32x16_bf16(ch[s], zl[s], acc, 0, 0, 0);
      acc = __builtin_amdgcn_mfma_f32_32x32x16_bf16(cl[s], zh[s], acc, 0, 0, 0);
    }
    const int tb = (2 * r + sp) * 32 + 4 * g;
#pragma unroll
    for (int q = 0; q < 4; ++q) {
      float4 rv = *reinterpret_cast<const float4*>(ws + tb + 8 * q);
      float ra[4] = {rv.x, rv.y, rv.z, rv.w};
#pragma unroll
      for (int j = 0; j < 4; ++j) {
        float sc = ra[j] + acc[4 * q + j];   // r2n + dot, maximize
        int kg = tb + 8 * q + j;
        if (sc > best) { best = sc; bidx = kg; }
      }
    }
    if (r < 127) {
      float xs[8] = {p0.x, p0.y, p0.z, p0.w, p1.x, p1.y, p1.z, p1.w};
      bf16x8 hi, lo;
#pragma unroll
      for (int j = 0; j < 8; ++j) {
        __bf16 h = (__bf16)xs[j];
        hi[j] = h; lo[j] = (__bf16)(xs[j] - (float)h);
      }
      unsigned wo = (unsigned)(buf ^ 1) * 32768u + st_off;
      *reinterpret_cast<bf16x8*>(lds + wo)        = hi;
      *reinterpret_cast<bf16x8*>(lds + wo + 8192) = lo;
    }
    __syncthreads();
  }
  {
    float ob = __shfl_xor(best, 32, 64);
    int   oi = __shfl_xor(bidx, 32, 64);
    if (ob > best || (ob == best && oi < bidx)) { best = ob; bidx = oi; }
  }
  float* mf  = reinterpret_cast<float*>(lds);
  int*   mi  = reinterpret_cast<int*>(lds + 1024);
  int*   mix = reinterpret_cast<int*>(lds + 2048);
  if (l < 32) { mf[w * 32 + c] = best; mi[w * 32 + c] = bidx; }
  __syncthreads();
  if (tid < 128) {
    int rgg = tid >> 5, rl = tid & 31;
    float b0 = mf[(2 * rgg) * 32 + rl];     int i0 = mi[(2 * rgg) * 32 + rl];
    float b1 = mf[(2 * rgg + 1) * 32 + rl]; int i1 = mi[(2 * rgg + 1) * 32 + rl];
    int idx = (b1 > b0 || (b1 == b0 && i1 < i0)) ? i1 : i0;
    mix[tid] = idx;
    out[NQ + 2 + rowbase + tid] = (float)idx;
  }
  __syncthreads();
  {
    const int row_l = tid >> 2, seg = tid & 3;
    const int idx  = mix[row_l];
    const int grow = rowbase + row_l;
    const float4* qp = reinterpret_cast<const float4*>(cb + (size_t)idx * D_DIM + seg * 16);
    const float4* zp = reinterpret_cast<const float4*>(z + (size_t)grow * D_DIM + seg * 16);
    float4*       op = reinterpret_cast<float4*>(out + (size_t)grow * D_DIM + seg * 16);
    float lp = 0.f;
#pragma unroll
    for (int cc = 0; cc < 4; ++cc) {
      float4 qv = qp[cc], zv = zp[cc];
      op[cc] = qv;
      float dx = zv.x - qv.x, dy = zv.y - qv.y;
      float dz = zv.z - qv.z, dw = zv.w - qv.w;
      lp += (dx * dx + dy * dy) + (dz * dz + dw * dw);
    }
#pragma unroll
    for (int off = 32; off > 0; off >>= 1) lp += __shfl_down(lp, off, 64);
    if (l == 0) atomicAdd(ws + WS_LOSS, lp);
  }
}

// ------------------------------------------------------------ finalize kernel
__global__ void vq_fin(const float* __restrict__ ws, float* __restrict__ out) {
  float mm = ws[WS_LOSS] * (1.0f / (float)(N_ROWS * D_DIM));
  out[NQ]     = mm;
  out[NQ + 1] = mm;
}

// -------------------------------------------------------------------- launch
extern "C" void kernel_launch(void* const* d_in, const int* in_sizes, int n_in,
                              void* d_out, int out_size, void* d_ws, size_t ws_size,
                              hipStream_t stream) {
  (void)in_sizes; (void)n_in; (void)out_size;
  const float* z  = (const float*)d_in[0];
  const float* cb = (const float*)d_in[1];
  float* out = (float*)d_out;
  float* ws  = (float*)d_ws;

  vq_prep<<<K_CB / 256, 256, 0, stream>>>(cb, ws);
  if (ws_size >= WS_NEED) {
    vq_split<<<256, 256, 0, stream>>>(cb, ws);
    vq_gd6<<<N_ROWS / 128, 512, 0, stream>>>(z, cb, ws, out);
  } else {
    vq_main_reg<<<N_ROWS / 128, 512, 0, stream>>>(z, cb, ws, out);
  }
  vq_fin<<<1, 1, 0, stream>>>(ws, out);
}

// Round 16
// 153.688 us; speedup vs baseline: 1.0537x; 1.0020x over previous
//
#include <hip/hip_runtime.h>
#include <cfloat>

// VQ-VAE nearest-codebook via bf16x3 split MFMA, v12 "R15 minus reg clamp":
//   - identical to R15 (double-buffered fragment sets, epilogue-fused acc
//     re-init, no setprio) but __launch_bounds__(512) WITHOUT a min-waves
//     bound: the (512,2) floor made the allocator clamp arch VGPRs at 128
//     and spill ~30MB (R15); unbounded, ~234 unified regs fit and 2
//     waves/SIMD still holds (512-reg SIMD pool / 234 = 2).
// d_out (f32): [0,NQ) quantized | [NQ] vq_loss | [NQ+1] commitment | [NQ+2,+N) idx
// d_ws  (f32): [0,K) r2n | [K] loss | [8448...) split codebook (2 MB)

typedef __bf16 bf16x8 __attribute__((ext_vector_type(8)));
typedef float  f32x16 __attribute__((ext_vector_type(16)));

constexpr int N_ROWS = 32768;
constexpr int K_CB   = 8192;
constexpr int D_DIM  = 64;
constexpr size_t NQ  = (size_t)N_ROWS * D_DIM;
constexpr int WS_LOSS = K_CB;
constexpr size_t WS_SPLIT_F   = 8448;
constexpr size_t SPLIT_BYTES  = (size_t)K_CB * D_DIM * 4;   // 2 MB
constexpr size_t WS_NEED      = WS_SPLIT_F * 4 + SPLIT_BYTES;

static __device__ __forceinline__ f32x16 MF(bf16x8 a, bf16x8 b, f32x16 c) {
  return __builtin_amdgcn_mfma_f32_32x32x16_bf16(a, b, c, 0, 0, 0);
}

// ---------------------------------------------------------------- prep: r2n
__global__ __launch_bounds__(256) void vq_prep(const float* __restrict__ cb,
                                               float* __restrict__ ws) {
  const int k = blockIdx.x * 256 + threadIdx.x;
  if (k == 0) ws[WS_LOSS] = 0.0f;
  const float4* p = reinterpret_cast<const float4*>(cb) + (size_t)k * 16;
  float s0 = 0.f, s1 = 0.f, s2 = 0.f, s3 = 0.f;
#pragma unroll
  for (int j = 0; j < 16; ++j) {
    float4 v = p[j];
    s0 = fmaf(v.x, v.x, s0); s1 = fmaf(v.y, v.y, s1);
    s2 = fmaf(v.z, v.z, s2); s3 = fmaf(v.w, v.w, s3);
  }
  ws[k] = -0.5f * ((s0 + s1) + (s2 + s3));   // r2n = -r2/2
}

// ------------------------------------------------- prep: split codebook in ws
// Round r (256 codes) -> 64KB block: t(=k>>5&7)*8192 + h*4096 + ch*512 + c*16.
__global__ __launch_bounds__(256) void vq_split(const float* __restrict__ cb,
                                                float* __restrict__ ws) {
  const int u  = blockIdx.x * 256 + threadIdx.x;   // 65536 threads
  const int k  = u >> 3, ch = u & 7;
  const int r  = k >> 8, t = (k >> 5) & 7, c = k & 31;
  const float* src = cb + (size_t)k * D_DIM + ch * 8;
  float4 f0 = *reinterpret_cast<const float4*>(src);
  float4 f1 = *reinterpret_cast<const float4*>(src + 4);
  float xs[8] = {f0.x, f0.y, f0.z, f0.w, f1.x, f1.y, f1.z, f1.w};
  bf16x8 hi, lo;
#pragma unroll
  for (int j = 0; j < 8; ++j) {
    __bf16 h = (__bf16)xs[j];
    hi[j] = h;
    lo[j] = (__bf16)(xs[j] - (float)h);
  }
  char* base = reinterpret_cast<char*>(ws + WS_SPLIT_F) +
               (size_t)r * 65536 + (size_t)t * 8192 + (size_t)ch * 512 + (size_t)c * 16;
  *reinterpret_cast<bf16x8*>(base)        = hi;
  *reinterpret_cast<bf16x8*>(base + 4096) = lo;
}

// ---------------------------------------------------------------- main kernel
__global__ __launch_bounds__(512) void vq_gd7(const float* __restrict__ z,
                                              const float* __restrict__ cb,
                                              float* __restrict__ ws,
                                              float* __restrict__ out) {
  __shared__ __attribute__((aligned(16))) unsigned char lds[12288];

  const int tid = threadIdx.x;
  const int w = tid >> 6, l = tid & 63;
  const int c = l & 31, g = l >> 5;
  const int rowbase = blockIdx.x * 128;

  // --- z fragments: 4 rowsets x 4 k-steps, hi/lo split, registers forever ---
  bf16x8 zh[4][4], zl[4][4];
#pragma unroll
  for (int q = 0; q < 4; ++q) {
    const float* zr = z + (size_t)(rowbase + q * 32 + c) * D_DIM + 8 * g;
#pragma unroll
    for (int s = 0; s < 4; ++s) {
      float4 f0 = *reinterpret_cast<const float4*>(zr + 16 * s);
      float4 f1 = *reinterpret_cast<const float4*>(zr + 16 * s + 4);
      float xs[8] = {f0.x, f0.y, f0.z, f0.w, f1.x, f1.y, f1.z, f1.w};
#pragma unroll
      for (int j = 0; j < 8; ++j) {
        __bf16 h = (__bf16)xs[j];
        zh[q][s][j] = h;
        zl[q][s][j] = (__bf16)(xs[j] - (float)h);
      }
    }
  }

  const char*  cbbase = reinterpret_cast<const char*>(ws + WS_SPLIT_F) +
                        (size_t)w * 8192 + (size_t)g * 512 + (size_t)c * 16;
  const float* rbase  = ws + w * 32 + 4 * g;

#define LOADF(FH, FL, RIDX)                                                    \
  do {                                                                         \
    const char* p_ = cbbase + (size_t)(RIDX) * 65536;                          \
    _Pragma("unroll")                                                          \
    for (int s = 0; s < 4; ++s) {                                              \
      FH[s] = *reinterpret_cast<const bf16x8*>(p_ + s * 1024);                 \
      FL[s] = *reinterpret_cast<const bf16x8*>(p_ + 4096 + s * 1024);          \
    }                                                                          \
  } while (0)

#define LOADRV(RIDX)                                                           \
  do {                                                                         \
    const float* q_ = rbase + (RIDX) * 256;                                    \
    rv0 = *reinterpret_cast<const float4*>(q_);                                \
    rv1 = *reinterpret_cast<const float4*>(q_ + 8);                            \
    rv2 = *reinterpret_cast<const float4*>(q_ + 16);                           \
    rv3 = *reinterpret_cast<const float4*>(q_ + 24);                           \
  } while (0)

#define MKINIT(DST)                                                            \
  do {                                                                         \
    DST[0]  = rv0.x; DST[1]  = rv0.y; DST[2]  = rv0.z; DST[3]  = rv0.w;        \
    DST[4]  = rv1.x; DST[5]  = rv1.y; DST[6]  = rv1.z; DST[7]  = rv1.w;        \
    DST[8]  = rv2.x; DST[9]  = rv2.y; DST[10] = rv2.z; DST[11] = rv2.w;        \
    DST[12] = rv3.x; DST[13] = rv3.y; DST[14] = rv3.z; DST[15] = rv3.w;        \
  } while (0)

#define CLUSTER(FH, FL)                                                        \
  do {                                                                         \
    _Pragma("unroll")                                                          \
    for (int s = 0; s < 4; ++s) {                                              \
      a0 = MF(FH[s], zh[0][s], a0); a1 = MF(FH[s], zh[1][s], a1);              \
      a2 = MF(FH[s], zh[2][s], a2); a3 = MF(FH[s], zh[3][s], a3);              \
      a0 = MF(FH[s], zl[0][s], a0); a1 = MF(FH[s], zl[1][s], a1);              \
      a2 = MF(FH[s], zl[2][s], a2); a3 = MF(FH[s], zl[3][s], a3);              \
      a0 = MF(FL[s], zh[0][s], a0); a1 = MF(FL[s], zh[1][s], a1);              \
      a2 = MF(FL[s], zh[2][s], a2); a3 = MF(FL[s], zh[3][s], a3);              \
    }                                                                          \
  } while (0)

// epilogue for one acc: tree-max, first-i scan, conditional update, re-init
#define EPI1(ACC, GB, BP, PB)                                                  \
  do {                                                                         \
    float m_ = ACC[0];                                                         \
    _Pragma("unroll")                                                          \
    for (int i = 1; i < 16; ++i) m_ = fmaxf(m_, ACC[i]);                       \
    int bi_ = 0;                                                               \
    _Pragma("unroll")                                                          \
    for (int i = 15; i >= 0; --i) bi_ = (ACC[i] == m_) ? i : bi_;              \
    if (m_ > GB) { GB = m_; BP = (PB) + bi_; }                                 \
    ACC = inx;                                                                 \
  } while (0)

#define EPI4(RR)                                                               \
  do {                                                                         \
    f32x16 inx;                                                                \
    MKINIT(inx);                                                               \
    const int pb_ = (RR) << 4;                                                 \
    EPI1(a0, gbest[0], bpack[0], pb_);                                         \
    EPI1(a1, gbest[1], bpack[1], pb_);                                         \
    EPI1(a2, gbest[2], bpack[2], pb_);                                         \
    EPI1(a3, gbest[3], bpack[3], pb_);                                         \
  } while (0)

  bf16x8 fhA[4], flA[4], fhB[4], flB[4];
  float4 rv0, rv1, rv2, rv3;
  f32x16 a0, a1, a2, a3;

  float gbest[4];
  int   bpack[4];
#pragma unroll
  for (int q = 0; q < 4; ++q) { gbest[q] = -FLT_MAX; bpack[q] = 0; }

  // prologue: round 0 fragments + rv(0) -> init accs
  LOADF(fhA, flA, 0);
  LOADRV(0);
  {
    f32x16 i0;
    MKINIT(i0);
    a0 = i0; a1 = i0; a2 = i0; a3 = i0;
  }

  for (int t = 0; t < 16; ++t) {
    const int r0 = 2 * t, r1 = 2 * t + 1;
    // even round r0: prefetch r1 into B, rv(r1) for re-init
    LOADF(fhB, flB, r1);
    LOADRV(r1);
    CLUSTER(fhA, flA);
    EPI4(r0);                       // update + re-init accs from rv(r1)
    // odd round r1: prefetch next even round into A (clamped), rv likewise
    const int r2 = (r1 < 31) ? r1 + 1 : 31;
    LOADF(fhA, flA, r2);
    LOADRV(r2);
    CLUSTER(fhB, flB);
    EPI4(r1);                       // update + re-init accs from rv(r2)
  }

#undef LOADF
#undef LOADRV
#undef MKINIT
#undef CLUSTER
#undef EPI1
#undef EPI4

  // --- decode packed (round,i) -> global k, then exact-tie merges (max) ---
  int bk[4];
#pragma unroll
  for (int q = 0; q < 4; ++q) {
    int rr = bpack[q] >> 4, i = bpack[q] & 15;
    int cid = (i & 3) + 8 * (i >> 2) + 4 * g;
    bk[q] = rr * 256 + w * 32 + cid;
  }
#pragma unroll
  for (int q = 0; q < 4; ++q) {
    float ob = __shfl_xor(gbest[q], 32, 64);
    int   ok = __shfl_xor(bk[q], 32, 64);
    if (ob > gbest[q] || (ob == gbest[q] && ok < bk[q])) { gbest[q] = ob; bk[q] = ok; }
  }

  float* fbuf = reinterpret_cast<float*>(lds);          // [8 tiles][128 rows]
  int*   kbuf = reinterpret_cast<int*>(lds + 4096);     // [8][128]
  int*   ibuf = reinterpret_cast<int*>(lds + 8192);     // [128]
  if (l < 32) {
#pragma unroll
    for (int q = 0; q < 4; ++q) {
      fbuf[w * 128 + q * 32 + l] = gbest[q];
      kbuf[w * 128 + q * 32 + l] = bk[q];
    }
  }
  __syncthreads();

  if (tid < 128) {
    float bb = fbuf[tid];
    int   kk = kbuf[tid];
#pragma unroll
    for (int ww = 1; ww < 8; ++ww) {
      float b2 = fbuf[ww * 128 + tid];
      int   k2 = kbuf[ww * 128 + tid];
      if (b2 > bb || (b2 == bb && k2 < kk)) { bb = b2; kk = k2; }
    }
    ibuf[tid] = kk;
    out[NQ + 2 + rowbase + tid] = (float)kk;
  }
  __syncthreads();

  // --- gather + losses: 4 threads per row ---
  {
    const int row_l = tid >> 2, seg = tid & 3;
    const int idx  = ibuf[row_l];
    const int grow = rowbase + row_l;
    const float4* qp = reinterpret_cast<const float4*>(cb + (size_t)idx * D_DIM + seg * 16);
    const float4* zp = reinterpret_cast<const float4*>(z + (size_t)grow * D_DIM + seg * 16);
    float4*       op = reinterpret_cast<float4*>(out + (size_t)grow * D_DIM + seg * 16);
    float lp = 0.f;
#pragma unroll
    for (int cc = 0; cc < 4; ++cc) {
      float4 qv = qp[cc], zv = zp[cc];
      op[cc] = qv;
      float dx = zv.x - qv.x, dy = zv.y - qv.y;
      float dz = zv.z - qv.z, dw = zv.w - qv.w;
      lp += (dx * dx + dy * dy) + (dz * dz + dw * dw);
    }
#pragma unroll
    for (int off = 32; off > 0; off >>= 1) lp += __shfl_down(lp, off, 64);
    if (l == 0) atomicAdd(ws + WS_LOSS, lp);
  }
}

// ------------------------------------------------- fallback (R4-style; adapted
// to r2n semantics: score = r2n + dot, maximize)
__global__ __launch_bounds__(512, 2) void vq_main_reg(const float* __restrict__ z,
                                                      const float* __restrict__ cb,
                                                      float* __restrict__ ws,
                                                      float* __restrict__ out) {
  __shared__ __attribute__((aligned(16))) unsigned char lds[65536];
  const int tid = threadIdx.x;
  const int w = tid >> 6, l = tid & 63;
  const int rg = w >> 1, sp = w & 1;
  const int c = l & 31, g = l >> 5;
  const int rowbase = blockIdx.x * 128;
  const int myrow = rowbase + rg * 32 + c;

  bf16x8 zh[4], zl[4];
#pragma unroll
  for (int s = 0; s < 4; ++s) {
    const float* zp = z + (size_t)myrow * D_DIM + 16 * s + 8 * g;
    float4 f0 = *reinterpret_cast<const float4*>(zp);
    float4 f1 = *reinterpret_cast<const float4*>(zp + 4);
    float xs[8] = {f0.x, f0.y, f0.z, f0.w, f1.x, f1.y, f1.z, f1.w};
#pragma unroll
    for (int j = 0; j < 8; ++j) {
      __bf16 h = (__bf16)xs[j];
      zh[s][j] = h; zl[s][j] = (__bf16)(xs[j] - (float)h);
    }
  }
  const int st_t01 = tid >> 8;
  const int st_c   = (tid >> 3) & 31;
  const int st_ch  = tid & 7;
  const unsigned st_off = (unsigned)(st_t01 * 16384 + st_ch * 512 + st_c * 16);
  const float* st_g = cb + (size_t)(st_t01 * 32 + st_c) * D_DIM + st_ch * 8;

  float best = -FLT_MAX;
  int   bidx = 0;
  float4 p0 = *reinterpret_cast<const float4*>(st_g);
  float4 p1 = *reinterpret_cast<const float4*>(st_g + 4);
  {
    float xs[8] = {p0.x, p0.y, p0.z, p0.w, p1.x, p1.y, p1.z, p1.w};
    bf16x8 hi, lo;
#pragma unroll
    for (int j = 0; j < 8; ++j) {
      __bf16 h = (__bf16)xs[j];
      hi[j] = h; lo[j] = (__bf16)(xs[j] - (float)h);
    }
    *reinterpret_cast<bf16x8*>(lds + st_off)        = hi;
    *reinterpret_cast<bf16x8*>(lds + st_off + 8192) = lo;
  }
  __syncthreads();
  const unsigned rd_base = (unsigned)(sp * 16384 + c * 16);
  for (int r = 0; r < 128; ++r) {
    const int buf = r & 1;
    if (r < 127) {
      const float* gp = st_g + (size_t)(r + 1) * (64 * D_DIM);
      p0 = *reinterpret_cast<const float4*>(gp);
      p1 = *reinterpret_cast<const float4*>(gp + 4);
    }
    const unsigned b0 = (unsigned)buf * 32768u + rd_base;
    bf16x8 ch[4], cl[4];
#pragma unroll
    for (int s = 0; s < 4; ++s) {
      unsigned off = b0 + (unsigned)((2 * s + g) * 512);
      ch[s] = *reinterpret_cast<const bf16x8*>(lds + off);
      cl[s] = *reinterpret_cast<const bf16x8*>(lds + off + 8192);
    }
    f32x16 acc;
#pragma unroll
    for (int i = 0; i < 16; ++i) acc[i] = 0.f;
#pragma unroll
    for (int s = 0; s < 4; ++s) {
      acc = __builtin_amdgcn_mfma_f32_32x32x16_bf16(ch[s], zh[s], acc, 0, 0, 0);
      acc = __builtin_amdgcn_mfma_f32_32x32x16_bf16(ch[s], zl[s], acc, 0, 0, 0);
      acc = __builtin_amdgcn_mfma_f32_32x32x16_bf16(cl[s], zh[s], acc, 0, 0, 0);
    }
    const int tb = (2 * r + sp) * 32 + 4 * g;
#pragma unroll
    for (int q = 0; q < 4; ++q) {
      float4 rv = *reinterpret_cast<const float4*>(ws + tb + 8 * q);
      float ra[4] = {rv.x, rv.y, rv.z, rv.w};
#pragma unroll
      for (int j = 0; j < 4; ++j) {
        float sc = ra[j] + acc[4 * q + j];   // r2n + dot, maximize
        int kg = tb + 8 * q + j;
        if (sc > best) { best = sc; bidx = kg; }
      }
    }
    if (r < 127) {
      float xs[8] = {p0.x, p0.y, p0.z, p0.w, p1.x, p1.y, p1.z, p1.w};
      bf16x8 hi, lo;
#pragma unroll
      for (int j = 0; j < 8; ++j) {
        __bf16 h = (__bf16)xs[j];
        hi[j] = h; lo[j] = (__bf16)(xs[j] - (float)h);
      }
      unsigned wo = (unsigned)(buf ^ 1) * 32768u + st_off;
      *reinterpret_cast<bf16x8*>(lds + wo)        = hi;
      *reinterpret_cast<bf16x8*>(lds + wo + 8192) = lo;
    }
    __syncthreads();
  }
  {
    float ob = __shfl_xor(best, 32, 64);
    int   oi = __shfl_xor(bidx, 32, 64);
    if (ob > best || (ob == best && oi < bidx)) { best = ob; bidx = oi; }
  }
  float* mf  = reinterpret_cast<float*>(lds);
  int*   mi  = reinterpret_cast<int*>(lds + 1024);
  int*   mix = reinterpret_cast<int*>(lds + 2048);
  if (l < 32) { mf[w * 32 + c] = best; mi[w * 32 + c] = bidx; }
  __syncthreads();
  if (tid < 128) {
    int rgg = tid >> 5, rl = tid & 31;
    float b0 = mf[(2 * rgg) * 32 + rl];     int i0 = mi[(2 * rgg) * 32 + rl];
    float b1 = mf[(2 * rgg + 1) * 32 + rl]; int i1 = mi[(2 * rgg + 1) * 32 + rl];
    int idx = (b1 > b0 || (b1 == b0 && i1 < i0)) ? i1 : i0;
    mix[tid] = idx;
    out[NQ + 2 + rowbase + tid] = (float)idx;
  }
  __syncthreads();
  {
    const int row_l = tid >> 2, seg = tid & 3;
    const int idx  = mix[row_l];
    const int grow = rowbase + row_l;
    const float4* qp = reinterpret_cast<const float4*>(cb + (size_t)idx * D_DIM + seg * 16);
    const float4* zp = reinterpret_cast<const float4*>(z + (size_t)grow * D_DIM + seg * 16);
    float4*       op = reinterpret_cast<float4*>(out + (size_t)grow * D_DIM + seg * 16);
    float lp = 0.f;
#pragma unroll
    for (int cc = 0; cc < 4; ++cc) {
      float4 qv = qp[cc], zv = zp[cc];
      op[cc] = qv;
      float dx = zv.x - qv.x, dy = zv.y - qv.y;
      float dz = zv.z - qv.z, dw = zv.w - qv.w;
      lp += (dx * dx + dy * dy) + (dz * dz + dw * dw);
    }
#pragma unroll
    for (int off = 32; off > 0; off >>= 1) lp += __shfl_down(lp, off, 64);
    if (l == 0) atomicAdd(ws + WS_LOSS, lp);
  }
}

// ------------------------------------------------------------ finalize kernel
__global__ void vq_fin(const float* __restrict__ ws, float* __restrict__ out) {
  float mm = ws[WS_LOSS] * (1.0f / (float)(N_ROWS * D_DIM));
  out[NQ]     = mm;
  out[NQ + 1] = mm;
}

// -------------------------------------------------------------------- launch
extern "C" void kernel_launch(void* const* d_in, const int* in_sizes, int n_in,
                              void* d_out, int out_size, void* d_ws, size_t ws_size,
                              hipStream_t stream) {
  (void)in_sizes; (void)n_in; (void)out_size;
  const float* z  = (const float*)d_in[0];
  const float* cb = (const float*)d_in[1];
  float* out = (float*)d_out;
  float* ws  = (float*)d_ws;

  vq_prep<<<K_CB / 256, 256, 0, stream>>>(cb, ws);
  if (ws_size >= WS_NEED) {
    vq_split<<<256, 256, 0, stream>>>(cb, ws);
    vq_gd7<<<N_ROWS / 128, 512, 0, stream>>>(z, cb, ws, out);
  } else {
    vq_main_reg<<<N_ROWS / 128, 512, 0, stream>>>(z, cb, ws, out);
  }
  vq_fin<<<1, 1, 0, stream>>>(ws, out);
}

// Round 17
// 149.844 us; speedup vs baseline: 1.0807x; 1.0257x over previous
//
#include <hip/hip_runtime.h>
#include <cfloat>

// VQ-VAE nearest-codebook via bf16x3 split MFMA, v13 "8 MFMA chains/wave":
//   - wave = 2 code-tiles x 4 rowsets = 8 accumulators (128 AGPR); chain dep
//     distance 8x32=256 cyc covers 32x32 MFMA latency (R5/R9/R10's 4-chain
//     configs all plateaued at ~36% MfmaUtil; 2-chain configs at ~28%)
//   - z frags in regs/AGPRs (128); code frags JIT per s-step (16 transient)
//   - round = 512 codes (16 tiles), 16 rounds; grid 256; barrier-free loop
//   - C-init accs from r2n (argmax semantics, proven R10-R16)
// d_out (f32): [0,NQ) quantized | [NQ] vq_loss | [NQ+1] commitment | [NQ+2,+N) idx
// d_ws  (f32): [0,K) r2n | [K] loss | [8448...) split codebook (2 MB)

typedef __bf16 bf16x8 __attribute__((ext_vector_type(8)));
typedef float  f32x16 __attribute__((ext_vector_type(16)));

constexpr int N_ROWS = 32768;
constexpr int K_CB   = 8192;
constexpr int D_DIM  = 64;
constexpr size_t NQ  = (size_t)N_ROWS * D_DIM;
constexpr int WS_LOSS = K_CB;
constexpr size_t WS_SPLIT_F   = 8448;
constexpr size_t SPLIT_BYTES  = (size_t)K_CB * D_DIM * 4;   // 2 MB
constexpr size_t WS_NEED      = WS_SPLIT_F * 4 + SPLIT_BYTES;

static __device__ __forceinline__ f32x16 MF(bf16x8 a, bf16x8 b, f32x16 c) {
  return __builtin_amdgcn_mfma_f32_32x32x16_bf16(a, b, c, 0, 0, 0);
}

// ---------------------------------------------------------------- prep: r2n
__global__ __launch_bounds__(256) void vq_prep(const float* __restrict__ cb,
                                               float* __restrict__ ws) {
  const int k = blockIdx.x * 256 + threadIdx.x;
  if (k == 0) ws[WS_LOSS] = 0.0f;
  const float4* p = reinterpret_cast<const float4*>(cb) + (size_t)k * 16;
  float s0 = 0.f, s1 = 0.f, s2 = 0.f, s3 = 0.f;
#pragma unroll
  for (int j = 0; j < 16; ++j) {
    float4 v = p[j];
    s0 = fmaf(v.x, v.x, s0); s1 = fmaf(v.y, v.y, s1);
    s2 = fmaf(v.z, v.z, s2); s3 = fmaf(v.w, v.w, s3);
  }
  ws[k] = -0.5f * ((s0 + s1) + (s2 + s3));   // r2n = -r2/2
}

// ------------------------------------------------- prep: split codebook in ws
// Linear in k: 8192B per 32-code tile; inside: h*4096 + ch*512 + c*16.
__global__ __launch_bounds__(256) void vq_split(const float* __restrict__ cb,
                                                float* __restrict__ ws) {
  const int u  = blockIdx.x * 256 + threadIdx.x;   // 65536 threads
  const int k  = u >> 3, ch = u & 7;
  const int tile = k >> 5, c = k & 31;
  const float* src = cb + (size_t)k * D_DIM + ch * 8;
  float4 f0 = *reinterpret_cast<const float4*>(src);
  float4 f1 = *reinterpret_cast<const float4*>(src + 4);
  float xs[8] = {f0.x, f0.y, f0.z, f0.w, f1.x, f1.y, f1.z, f1.w};
  bf16x8 hi, lo;
#pragma unroll
  for (int j = 0; j < 8; ++j) {
    __bf16 h = (__bf16)xs[j];
    hi[j] = h;
    lo[j] = (__bf16)(xs[j] - (float)h);
  }
  char* base = reinterpret_cast<char*>(ws + WS_SPLIT_F) +
               (size_t)tile * 8192 + (size_t)ch * 512 + (size_t)c * 16;
  *reinterpret_cast<bf16x8*>(base)        = hi;
  *reinterpret_cast<bf16x8*>(base + 4096) = lo;
}

// ---------------------------------------------------------------- main kernel
// 512 thr = 8 waves; wave w = tiles {2w, 2w+1} of each 512-code round;
// 4 rowsets (128 rows/block). 8 acc chains. 16 rounds. Grid 256.
__global__ __launch_bounds__(512) void vq_c8(const float* __restrict__ z,
                                             const float* __restrict__ cb,
                                             float* __restrict__ ws,
                                             float* __restrict__ out) {
  __shared__ __attribute__((aligned(16))) unsigned char lds[12288];

  const int tid = threadIdx.x;
  const int w = tid >> 6, l = tid & 63;
  const int c = l & 31, g = l >> 5;
  const int rowbase = blockIdx.x * 128;

  // --- z fragments: 4 rowsets x 4 k-steps, hi/lo split, registers forever ---
  bf16x8 zh[4][4], zl[4][4];
#pragma unroll
  for (int q = 0; q < 4; ++q) {
    const float* zr = z + (size_t)(rowbase + q * 32 + c) * D_DIM + 8 * g;
#pragma unroll
    for (int s = 0; s < 4; ++s) {
      float4 f0 = *reinterpret_cast<const float4*>(zr + 16 * s);
      float4 f1 = *reinterpret_cast<const float4*>(zr + 16 * s + 4);
      float xs[8] = {f0.x, f0.y, f0.z, f0.w, f1.x, f1.y, f1.z, f1.w};
#pragma unroll
      for (int j = 0; j < 8; ++j) {
        __bf16 h = (__bf16)xs[j];
        zh[q][s][j] = h;
        zl[q][s][j] = (__bf16)(xs[j] - (float)h);
      }
    }
  }

  // tile-pair base: tile T = r*16 + 2w + tt at byte T*8192; lane part g,c
  const char*  cbbase = reinterpret_cast<const char*>(ws + WS_SPLIT_F) +
                        (size_t)(2 * w) * 8192 + (size_t)g * 512 + (size_t)c * 16;
  const float* rbase  = ws + w * 64 + 4 * g;

  float gbest[4];
  int   bpack[4];   // (round<<5) | (tt<<4) | i
#pragma unroll
  for (int q = 0; q < 4; ++q) { gbest[q] = -FLT_MAX; bpack[q] = 0; }

  f32x16 a00, a01, a02, a03, a10, a11, a12, a13;

  for (int r = 0; r < 16; ++r) {
    // --- C-init from r2n: tile0 -> inx0 (a0x), tile1 -> inx1 (a1x) ---
    {
      const float* rp = rbase + r * 512;
      float4 p0 = *reinterpret_cast<const float4*>(rp);
      float4 p1 = *reinterpret_cast<const float4*>(rp + 8);
      float4 p2 = *reinterpret_cast<const float4*>(rp + 16);
      float4 p3 = *reinterpret_cast<const float4*>(rp + 24);
      float4 p4 = *reinterpret_cast<const float4*>(rp + 32);
      float4 p5 = *reinterpret_cast<const float4*>(rp + 40);
      float4 p6 = *reinterpret_cast<const float4*>(rp + 48);
      float4 p7 = *reinterpret_cast<const float4*>(rp + 56);
      f32x16 i0, i1;
      i0[0] = p0.x; i0[1] = p0.y; i0[2]  = p0.z; i0[3]  = p0.w;
      i0[4] = p1.x; i0[5] = p1.y; i0[6]  = p1.z; i0[7]  = p1.w;
      i0[8] = p2.x; i0[9] = p2.y; i0[10] = p2.z; i0[11] = p2.w;
      i0[12] = p3.x; i0[13] = p3.y; i0[14] = p3.z; i0[15] = p3.w;
      i1[0] = p4.x; i1[1] = p4.y; i1[2]  = p4.z; i1[3]  = p4.w;
      i1[4] = p5.x; i1[5] = p5.y; i1[6]  = p5.z; i1[7]  = p5.w;
      i1[8] = p6.x; i1[9] = p6.y; i1[10] = p6.z; i1[11] = p6.w;
      i1[12] = p7.x; i1[13] = p7.y; i1[14] = p7.z; i1[15] = p7.w;
      a00 = i0; a01 = i0; a02 = i0; a03 = i0;
      a10 = i1; a11 = i1; a12 = i1; a13 = i1;
    }

    // --- cluster: 4 s-steps x (3 terms x 8 chains) = 96 MFMA ---
    const char* cb_ = cbbase + (size_t)r * 131072;
#pragma unroll
    for (int s = 0; s < 4; ++s) {
      bf16x8 fh0 = *reinterpret_cast<const bf16x8*>(cb_ + s * 1024);
      bf16x8 fl0 = *reinterpret_cast<const bf16x8*>(cb_ + 4096 + s * 1024);
      bf16x8 fh1 = *reinterpret_cast<const bf16x8*>(cb_ + 8192 + s * 1024);
      bf16x8 fl1 = *reinterpret_cast<const bf16x8*>(cb_ + 12288 + s * 1024);
      a00 = MF(fh0, zh[0][s], a00); a01 = MF(fh0, zh[1][s], a01);
      a02 = MF(fh0, zh[2][s], a02); a03 = MF(fh0, zh[3][s], a03);
      a10 = MF(fh1, zh[0][s], a10); a11 = MF(fh1, zh[1][s], a11);
      a12 = MF(fh1, zh[2][s], a12); a13 = MF(fh1, zh[3][s], a13);
      a00 = MF(fh0, zl[0][s], a00); a01 = MF(fh0, zl[1][s], a01);
      a02 = MF(fh0, zl[2][s], a02); a03 = MF(fh0, zl[3][s], a03);
      a10 = MF(fh1, zl[0][s], a10); a11 = MF(fh1, zl[1][s], a11);
      a12 = MF(fh1, zl[2][s], a12); a13 = MF(fh1, zl[3][s], a13);
      a00 = MF(fl0, zh[0][s], a00); a01 = MF(fl0, zh[1][s], a01);
      a02 = MF(fl0, zh[2][s], a02); a03 = MF(fl0, zh[3][s], a03);
      a10 = MF(fl1, zh[0][s], a10); a11 = MF(fl1, zh[1][s], a11);
      a12 = MF(fl1, zh[2][s], a12); a13 = MF(fl1, zh[3][s], a13);
    }

    // --- epilogue: tile0 accs first (smaller k), then tile1; strict '>' ---
#define EPI1(ACC, GB, BP, PB)                                                  \
    do {                                                                       \
      float m_ = ACC[0];                                                       \
      _Pragma("unroll")                                                        \
      for (int i = 1; i < 16; ++i) m_ = fmaxf(m_, ACC[i]);                     \
      int bi_ = 0;                                                             \
      _Pragma("unroll")                                                        \
      for (int i = 15; i >= 0; --i) bi_ = (ACC[i] == m_) ? i : bi_;            \
      if (m_ > GB) { GB = m_; BP = (PB) + bi_; }                               \
    } while (0)

    const int pb0 = (r << 5);
    const int pb1 = (r << 5) | 16;
    EPI1(a00, gbest[0], bpack[0], pb0);
    EPI1(a01, gbest[1], bpack[1], pb0);
    EPI1(a02, gbest[2], bpack[2], pb0);
    EPI1(a03, gbest[3], bpack[3], pb0);
    EPI1(a10, gbest[0], bpack[0], pb1);
    EPI1(a11, gbest[1], bpack[1], pb1);
    EPI1(a12, gbest[2], bpack[2], pb1);
    EPI1(a13, gbest[3], bpack[3], pb1);
#undef EPI1
  }

  // --- decode packed (round,tt,i) -> global k, then exact-tie merges (max) ---
  int bk[4];
#pragma unroll
  for (int q = 0; q < 4; ++q) {
    int rr = bpack[q] >> 5, tt = (bpack[q] >> 4) & 1, i = bpack[q] & 15;
    int cid = (i & 3) + 8 * (i >> 2) + 4 * g;
    bk[q] = rr * 512 + w * 64 + tt * 32 + cid;
  }
#pragma unroll
  for (int q = 0; q < 4; ++q) {
    float ob = __shfl_xor(gbest[q], 32, 64);
    int   ok = __shfl_xor(bk[q], 32, 64);
    if (ob > gbest[q] || (ob == gbest[q] && ok < bk[q])) { gbest[q] = ob; bk[q] = ok; }
  }

  float* fbuf = reinterpret_cast<float*>(lds);          // [8 waves][128 rows]
  int*   kbuf = reinterpret_cast<int*>(lds + 4096);     // [8][128]
  int*   ibuf = reinterpret_cast<int*>(lds + 8192);     // [128]
  if (l < 32) {
#pragma unroll
    for (int q = 0; q < 4; ++q) {
      fbuf[w * 128 + q * 32 + l] = gbest[q];
      kbuf[w * 128 + q * 32 + l] = bk[q];
    }
  }
  __syncthreads();

  if (tid < 128) {
    float bb = fbuf[tid];
    int   kk = kbuf[tid];
#pragma unroll
    for (int ww = 1; ww < 8; ++ww) {
      float b2 = fbuf[ww * 128 + tid];
      int   k2 = kbuf[ww * 128 + tid];
      if (b2 > bb || (b2 == bb && k2 < kk)) { bb = b2; kk = k2; }
    }
    ibuf[tid] = kk;
    out[NQ + 2 + rowbase + tid] = (float)kk;
  }
  __syncthreads();

  // --- gather + losses: 4 threads per row ---
  {
    const int row_l = tid >> 2, seg = tid & 3;
    const int idx  = ibuf[row_l];
    const int grow = rowbase + row_l;
    const float4* qp = reinterpret_cast<const float4*>(cb + (size_t)idx * D_DIM + seg * 16);
    const float4* zp = reinterpret_cast<const float4*>(z + (size_t)grow * D_DIM + seg * 16);
    float4*       op = reinterpret_cast<float4*>(out + (size_t)grow * D_DIM + seg * 16);
    float lp = 0.f;
#pragma unroll
    for (int cc = 0; cc < 4; ++cc) {
      float4 qv = qp[cc], zv = zp[cc];
      op[cc] = qv;
      float dx = zv.x - qv.x, dy = zv.y - qv.y;
      float dz = zv.z - qv.z, dw = zv.w - qv.w;
      lp += (dx * dx + dy * dy) + (dz * dz + dw * dw);
    }
#pragma unroll
    for (int off = 32; off > 0; off >>= 1) lp += __shfl_down(lp, off, 64);
    if (l == 0) atomicAdd(ws + WS_LOSS, lp);
  }
}

// ------------------------------------------------- fallback (R4-style; adapted
// to r2n semantics: score = r2n + dot, maximize)
__global__ __launch_bounds__(512, 2) void vq_main_reg(const float* __restrict__ z,
                                                      const float* __restrict__ cb,
                                                      float* __restrict__ ws,
                                                      float* __restrict__ out) {
  __shared__ __attribute__((aligned(16))) unsigned char lds[65536];
  const int tid = threadIdx.x;
  const int w = tid >> 6, l = tid & 63;
  const int rg = w >> 1, sp = w & 1;
  const int c = l & 31, g = l >> 5;
  const int rowbase = blockIdx.x * 128;
  const int myrow = rowbase + rg * 32 + c;

  bf16x8 zh[4], zl[4];
#pragma unroll
  for (int s = 0; s < 4; ++s) {
    const float* zp = z + (size_t)myrow * D_DIM + 16 * s + 8 * g;
    float4 f0 = *reinterpret_cast<const float4*>(zp);
    float4 f1 = *reinterpret_cast<const float4*>(zp + 4);
    float xs[8] = {f0.x, f0.y, f0.z, f0.w, f1.x, f1.y, f1.z, f1.w};
#pragma unroll
    for (int j = 0; j < 8; ++j) {
      __bf16 h = (__bf16)xs[j];
      zh[s][j] = h; zl[s][j] = (__bf16)(xs[j] - (float)h);
    }
  }
  // NOTE: fallback expects the R4-era per-round split layout; regenerate it
  // locally from cb (works regardless of ws split layout).
  const int st_t01 = tid >> 8;
  const int st_c   = (tid >> 3) & 31;
  const int st_ch  = tid & 7;
  const unsigned st_off = (unsigned)(st_t01 * 16384 + st_ch * 512 + st_c * 16);
  const float* st_g = cb + (size_t)(st_t01 * 32 + st_c) * D_DIM + st_ch * 8;

  float best = -FLT_MAX;
  int   bidx = 0;
  float4 p0 = *reinterpret_cast<const float4*>(st_g);
  float4 p1 = *reinterpret_cast<const float4*>(st_g + 4);
  {
    float xs[8] = {p0.x, p0.y, p0.z, p0.w, p1.x, p1.y, p1.z, p1.w};
    bf16x8 hi, lo;
#pragma unroll
    for (int j = 0; j < 8; ++j) {
      __bf16 h = (__bf16)xs[j];
      hi[j] = h; lo[j] = (__bf16)(xs[j] - (float)h);
    }
    *reinterpret_cast<bf16x8*>(lds + st_off)        = hi;
    *reinterpret_cast<bf16x8*>(lds + st_off + 8192) = lo;
  }
  __syncthreads();
  const unsigned rd_base = (unsigned)(sp * 16384 + c * 16);
  for (int r = 0; r < 128; ++r) {
    const int buf = r & 1;
    if (r < 127) {
      const float* gp = st_g + (size_t)(r + 1) * (64 * D_DIM);
      p0 = *reinterpret_cast<const float4*>(gp);
      p1 = *reinterpret_cast<const float4*>(gp + 4);
    }
    const unsigned b0 = (unsigned)buf * 32768u + rd_base;
    bf16x8 ch[4], cl[4];
#pragma unroll
    for (int s = 0; s < 4; ++s) {
      unsigned off = b0 + (unsigned)((2 * s + g) * 512);
      ch[s] = *reinterpret_cast<const bf16x8*>(lds + off);
      cl[s] = *reinterpret_cast<const bf16x8*>(lds + off + 8192);
    }
    f32x16 acc;
#pragma unroll
    for (int i = 0; i < 16; ++i) acc[i] = 0.f;
#pragma unroll
    for (int s = 0; s < 4; ++s) {
      acc = __builtin_amdgcn_mfma_f32_32x32x16_bf16(ch[s], zh[s], acc, 0, 0, 0);
      acc = __builtin_amdgcn_mfma_f32_32x32x16_bf16(ch[s], zl[s], acc, 0, 0, 0);
      acc = __builtin_amdgcn_mfma_f32_32x32x16_bf16(cl[s], zh[s], acc, 0, 0, 0);
    }
    const int tb = (2 * r + sp) * 32 + 4 * g;
#pragma unroll
    for (int q = 0; q < 4; ++q) {
      float4 rv = *reinterpret_cast<const float4*>(ws + tb + 8 * q);
      float ra[4] = {rv.x, rv.y, rv.z, rv.w};
#pragma unroll
      for (int j = 0; j < 4; ++j) {
        float sc = ra[j] + acc[4 * q + j];   // r2n + dot, maximize
        int kg = tb + 8 * q + j;
        if (sc > best) { best = sc; bidx = kg; }
      }
    }
    if (r < 127) {
      float xs[8] = {p0.x, p0.y, p0.z, p0.w, p1.x, p1.y, p1.z, p1.w};
      bf16x8 hi, lo;
#pragma unroll
      for (int j = 0; j < 8; ++j) {
        __bf16 h = (__bf16)xs[j];
        hi[j] = h; lo[j] = (__bf16)(xs[j] - (float)h);
      }
      unsigned wo = (unsigned)(buf ^ 1) * 32768u + st_off;
      *reinterpret_cast<bf16x8*>(lds + wo)        = hi;
      *reinterpret_cast<bf16x8*>(lds + wo + 8192) = lo;
    }
    __syncthreads();
  }
  {
    float ob = __shfl_xor(best, 32, 64);
    int   oi = __shfl_xor(bidx, 32, 64);
    if (ob > best || (ob == best && oi < bidx)) { best = ob; bidx = oi; }
  }
  float* mf  = reinterpret_cast<float*>(lds);
  int*   mi  = reinterpret_cast<int*>(lds + 1024);
  int*   mix = reinterpret_cast<int*>(lds + 2048);
  if (l < 32) { mf[w * 32 + c] = best; mi[w * 32 + c] = bidx; }
  __syncthreads();
  if (tid < 128) {
    int rgg = tid >> 5, rl = tid & 31;
    float b0 = mf[(2 * rgg) * 32 + rl];     int i0 = mi[(2 * rgg) * 32 + rl];
    float b1 = mf[(2 * rgg + 1) * 32 + rl]; int i1 = mi[(2 * rgg + 1) * 32 + rl];
    int idx = (b1 > b0 || (b1 == b0 && i1 < i0)) ? i1 : i0;
    mix[tid] = idx;
    out[NQ + 2 + rowbase + tid] = (float)idx;
  }
  __syncthreads();
  {
    const int row_l = tid >> 2, seg = tid & 3;
    const int idx  = mix[row_l];
    const int grow = rowbase + row_l;
    const float4* qp = reinterpret_cast<const float4*>(cb + (size_t)idx * D_DIM + seg * 16);
    const float4* zp = reinterpret_cast<const float4*>(z + (size_t)grow * D_DIM + seg * 16);
    float4*       op = reinterpret_cast<float4*>(out + (size_t)grow * D_DIM + seg * 16);
    float lp = 0.f;
#pragma unroll
    for (int cc = 0; cc < 4; ++cc) {
      float4 qv = qp[cc], zv = zp[cc];
      op[cc] = qv;
      float dx = zv.x - qv.x, dy = zv.y - qv.y;
      float dz = zv.z - qv.z, dw = zv.w - qv.w;
      lp += (dx * dx + dy * dy) + (dz * dz + dw * dw);
    }
#pragma unroll
    for (int off = 32; off > 0; off >>= 1) lp += __shfl_down(lp, off, 64);
    if (l == 0) atomicAdd(ws + WS_LOSS, lp);
  }
}

// ------------------------------------------------------------ finalize kernel
__global__ void vq_fin(const float* __restrict__ ws, float* __restrict__ out) {
  float mm = ws[WS_LOSS] * (1.0f / (float)(N_ROWS * D_DIM));
  out[NQ]     = mm;
  out[NQ + 1] = mm;
}

// -------------------------------------------------------------------- launch
extern "C" void kernel_launch(void* const* d_in, const int* in_sizes, int n_in,
                              void* d_out, int out_size, void* d_ws, size_t ws_size,
                              hipStream_t stream) {
  (void)in_sizes; (void)n_in; (void)out_size;
  const float* z  = (const float*)d_in[0];
  const float* cb = (const float*)d_in[1];
  float* out = (float*)d_out;
  float* ws  = (float*)d_ws;

  vq_prep<<<K_CB / 256, 256, 0, stream>>>(cb, ws);
  if (ws_size >= WS_NEED) {
    vq_split<<<256, 256, 0, stream>>>(cb, ws);
    vq_c8<<<N_ROWS / 128, 512, 0, stream>>>(z, cb, ws, out);
  } else {
    vq_main_reg<<<N_ROWS / 128, 512, 0, stream>>>(z, cb, ws, out);
  }
  vq_fin<<<1, 1, 0, stream>>>(ws, out);
}

// Round 18
// 136.481 us; speedup vs baseline: 1.1865x; 1.0979x over previous
//
#include <hip/hip_runtime.h>
#include <cfloat>

// VQ-VAE nearest-codebook via bf16x3 split MFMA, v14 "R10 + deferred argmax":
//   - R10 structure verbatim (4 chains, 128 rows/block, grid 256, 32 rounds,
//     prefetch-after-cluster, setprio) -- best measured config (129.4 us)
//   - in-loop epilogue reduced to tree-max + round tracking (no index scan);
//     winning round's chain recomputed bit-exactly after the loop (~3% tail)
//     to recover the element index. Cuts the critical-path VALU ~3x.
// d_out (f32): [0,NQ) quantized | [NQ] vq_loss | [NQ+1] commitment | [NQ+2,+N) idx
// d_ws  (f32): [0,K) r2n | [K] loss | [8448...) split codebook (2 MB)

typedef __bf16 bf16x8 __attribute__((ext_vector_type(8)));
typedef float  f32x16 __attribute__((ext_vector_type(16)));

constexpr int N_ROWS = 32768;
constexpr int K_CB   = 8192;
constexpr int D_DIM  = 64;
constexpr size_t NQ  = (size_t)N_ROWS * D_DIM;
constexpr int WS_LOSS = K_CB;
constexpr size_t WS_SPLIT_F   = 8448;
constexpr size_t SPLIT_BYTES  = (size_t)K_CB * D_DIM * 4;   // 2 MB
constexpr size_t WS_NEED      = WS_SPLIT_F * 4 + SPLIT_BYTES;
constexpr int NROUND = K_CB / 256;                          // 32 rounds of 256 codes

static __device__ __forceinline__ f32x16 MF(bf16x8 a, bf16x8 b, f32x16 c) {
  return __builtin_amdgcn_mfma_f32_32x32x16_bf16(a, b, c, 0, 0, 0);
}

// ---------------------------------------------------------------- prep: r2n
__global__ __launch_bounds__(256) void vq_prep(const float* __restrict__ cb,
                                               float* __restrict__ ws) {
  const int k = blockIdx.x * 256 + threadIdx.x;
  if (k == 0) ws[WS_LOSS] = 0.0f;
  const float4* p = reinterpret_cast<const float4*>(cb) + (size_t)k * 16;
  float s0 = 0.f, s1 = 0.f, s2 = 0.f, s3 = 0.f;
#pragma unroll
  for (int j = 0; j < 16; ++j) {
    float4 v = p[j];
    s0 = fmaf(v.x, v.x, s0); s1 = fmaf(v.y, v.y, s1);
    s2 = fmaf(v.z, v.z, s2); s3 = fmaf(v.w, v.w, s3);
  }
  ws[k] = -0.5f * ((s0 + s1) + (s2 + s3));   // r2n = -r2/2
}

// ------------------------------------------------- prep: split codebook in ws
// Round r (256 codes) -> 64KB block: t(=k>>5&7)*8192 + h*4096 + ch*512 + c*16.
__global__ __launch_bounds__(256) void vq_split(const float* __restrict__ cb,
                                                float* __restrict__ ws) {
  const int u  = blockIdx.x * 256 + threadIdx.x;   // 65536 threads
  const int k  = u >> 3, ch = u & 7;
  const int r  = k >> 8, t = (k >> 5) & 7, c = k & 31;
  const float* src = cb + (size_t)k * D_DIM + ch * 8;
  float4 f0 = *reinterpret_cast<const float4*>(src);
  float4 f1 = *reinterpret_cast<const float4*>(src + 4);
  float xs[8] = {f0.x, f0.y, f0.z, f0.w, f1.x, f1.y, f1.z, f1.w};
  bf16x8 hi, lo;
#pragma unroll
  for (int j = 0; j < 8; ++j) {
    __bf16 h = (__bf16)xs[j];
    hi[j] = h;
    lo[j] = (__bf16)(xs[j] - (float)h);
  }
  char* base = reinterpret_cast<char*>(ws + WS_SPLIT_F) +
               (size_t)r * 65536 + (size_t)t * 8192 + (size_t)ch * 512 + (size_t)c * 16;
  *reinterpret_cast<bf16x8*>(base)        = hi;
  *reinterpret_cast<bf16x8*>(base + 4096) = lo;
}

// ---------------------------------------------------------------- main kernel
__global__ __launch_bounds__(512, 2) void vq_dm(const float* __restrict__ z,
                                                const float* __restrict__ cb,
                                                float* __restrict__ ws,
                                                float* __restrict__ out) {
  __shared__ __attribute__((aligned(16))) unsigned char lds[12288];

  const int tid = threadIdx.x;
  const int w = tid >> 6, l = tid & 63;
  const int c = l & 31, g = l >> 5;
  const int rowbase = blockIdx.x * 128;

  // --- z fragments: 4 rowsets x 4 k-steps, hi/lo split, registers forever ---
  bf16x8 zh[4][4], zl[4][4];
#pragma unroll
  for (int q = 0; q < 4; ++q) {
    const float* zr = z + (size_t)(rowbase + q * 32 + c) * D_DIM + 8 * g;
#pragma unroll
    for (int s = 0; s < 4; ++s) {
      float4 f0 = *reinterpret_cast<const float4*>(zr + 16 * s);
      float4 f1 = *reinterpret_cast<const float4*>(zr + 16 * s + 4);
      float xs[8] = {f0.x, f0.y, f0.z, f0.w, f1.x, f1.y, f1.z, f1.w};
#pragma unroll
      for (int j = 0; j < 8; ++j) {
        __bf16 h = (__bf16)xs[j];
        zh[q][s][j] = h;
        zl[q][s][j] = (__bf16)(xs[j] - (float)h);
      }
    }
  }

  // code-fragment pointers for my tile: hi at +s*1024, lo +4096
  const char*  hpbase = reinterpret_cast<const char*>(ws + WS_SPLIT_F) +
                        (size_t)w * 8192 + (size_t)g * 512 + (size_t)c * 16;
  const float* rpbase = ws + w * 32 + 4 * g;
  const char*  hp = hpbase;
  const char*  lq = hpbase + 4096;
  const float* rp = rpbase;

  // prologue: round-0 fragments + r2n
  bf16x8 fh[4], fl[4];
#pragma unroll
  for (int s = 0; s < 4; ++s) {
    fh[s] = *reinterpret_cast<const bf16x8*>(hp + s * 1024);
    fl[s] = *reinterpret_cast<const bf16x8*>(lq + s * 1024);
  }
  float4 rv0 = *reinterpret_cast<const float4*>(rp);
  float4 rv1 = *reinterpret_cast<const float4*>(rp + 8);
  float4 rv2 = *reinterpret_cast<const float4*>(rp + 16);
  float4 rv3 = *reinterpret_cast<const float4*>(rp + 24);

  float gbest[4];
  int   bround[4];
#pragma unroll
  for (int q = 0; q < 4; ++q) { gbest[q] = -FLT_MAX; bround[q] = 0; }

  for (int r = 0; r < NROUND; ++r) {
    // C-init: acc = r2n (same 16 codes for all 4 row-accs)
    f32x16 ainit;
    ainit[0] = rv0.x; ainit[1] = rv0.y; ainit[2]  = rv0.z; ainit[3]  = rv0.w;
    ainit[4] = rv1.x; ainit[5] = rv1.y; ainit[6]  = rv1.z; ainit[7]  = rv1.w;
    ainit[8] = rv2.x; ainit[9] = rv2.y; ainit[10] = rv2.z; ainit[11] = rv2.w;
    ainit[12] = rv3.x; ainit[13] = rv3.y; ainit[14] = rv3.z; ainit[15] = rv3.w;
    f32x16 a0 = ainit, a1 = ainit, a2 = ainit, a3 = ainit;

    __builtin_amdgcn_s_setprio(1);
#pragma unroll
    for (int s = 0; s < 4; ++s) {
      a0 = MF(fh[s], zh[0][s], a0);
      a1 = MF(fh[s], zh[1][s], a1);
      a2 = MF(fh[s], zh[2][s], a2);
      a3 = MF(fh[s], zh[3][s], a3);
      a0 = MF(fh[s], zl[0][s], a0);
      a1 = MF(fh[s], zl[1][s], a1);
      a2 = MF(fh[s], zl[2][s], a2);
      a3 = MF(fh[s], zl[3][s], a3);
      a0 = MF(fl[s], zh[0][s], a0);
      a1 = MF(fl[s], zh[1][s], a1);
      a2 = MF(fl[s], zh[2][s], a2);
      a3 = MF(fl[s], zh[3][s], a3);
    }
    __builtin_amdgcn_s_setprio(0);

    // prefetch next round (WAR after cluster reads; latency hides under epilogue)
    if (r < NROUND - 1) {
      hp += 65536; lq += 65536; rp += 256;
#pragma unroll
      for (int s = 0; s < 4; ++s) {
        fh[s] = *reinterpret_cast<const bf16x8*>(hp + s * 1024);
        fl[s] = *reinterpret_cast<const bf16x8*>(lq + s * 1024);
      }
      rv0 = *reinterpret_cast<const float4*>(rp);
      rv1 = *reinterpret_cast<const float4*>(rp + 8);
      rv2 = *reinterpret_cast<const float4*>(rp + 16);
      rv3 = *reinterpret_cast<const float4*>(rp + 24);
    }

    // cheap epilogue: per acc, tree-max + round tracking only (no index scan)
#pragma unroll
    for (int q = 0; q < 4; ++q) {
      const f32x16& a = (q == 0) ? a0 : (q == 1) ? a1 : (q == 2) ? a2 : a3;
      float m = fmaxf(fmaxf(fmaxf(a[0], a[1]), fmaxf(a[2], a[3])),
                      fmaxf(fmaxf(a[4], a[5]), fmaxf(a[6], a[7])));
      float m2 = fmaxf(fmaxf(fmaxf(a[8], a[9]), fmaxf(a[10], a[11])),
                       fmaxf(fmaxf(a[12], a[13]), fmaxf(a[14], a[15])));
      m = fmaxf(m, m2);
      if (m > gbest[q]) { gbest[q] = m; bround[q] = r; }  // strict: earliest round
    }
  }

  // --- tail: recompute winning round's chain per acc (bit-exact) and scan ---
  int bk[4];
#pragma unroll
  for (int q = 0; q < 4; ++q) {
    const int rr = bround[q];
    const float* rp2 = rpbase + rr * 256;
    float4 v0 = *reinterpret_cast<const float4*>(rp2);
    float4 v1 = *reinterpret_cast<const float4*>(rp2 + 8);
    float4 v2 = *reinterpret_cast<const float4*>(rp2 + 16);
    float4 v3 = *reinterpret_cast<const float4*>(rp2 + 24);
    f32x16 acc;
    acc[0] = v0.x; acc[1] = v0.y; acc[2]  = v0.z; acc[3]  = v0.w;
    acc[4] = v1.x; acc[5] = v1.y; acc[6]  = v1.z; acc[7]  = v1.w;
    acc[8] = v2.x; acc[9] = v2.y; acc[10] = v2.z; acc[11] = v2.w;
    acc[12] = v3.x; acc[13] = v3.y; acc[14] = v3.z; acc[15] = v3.w;
    const char* hp2 = hpbase + (size_t)rr * 65536;
#pragma unroll
    for (int s = 0; s < 4; ++s) {
      bf16x8 f_h = *reinterpret_cast<const bf16x8*>(hp2 + s * 1024);
      bf16x8 f_l = *reinterpret_cast<const bf16x8*>(hp2 + 4096 + s * 1024);
      // EXACT accumulation order of the main cluster for this chain:
      acc = MF(f_h, zh[q][s], acc);
      acc = MF(f_h, zl[q][s], acc);
      acc = MF(f_l, zh[q][s], acc);
    }
    int bi = 0;
#pragma unroll
    for (int i = 15; i >= 0; --i) bi = (acc[i] == gbest[q]) ? i : bi;  // smallest i
    bk[q] = rr * 256 + w * 32 + (bi & 3) + 8 * (bi >> 2) + 4 * g;
  }

  // merge the two g-halves (same rows, disjoint codes)
#pragma unroll
  for (int q = 0; q < 4; ++q) {
    float ob = __shfl_xor(gbest[q], 32, 64);
    int   ok = __shfl_xor(bk[q], 32, 64);
    if (ob > gbest[q] || (ob == gbest[q] && ok < bk[q])) { gbest[q] = ob; bk[q] = ok; }
  }

  float* fbuf = reinterpret_cast<float*>(lds);          // [8 tiles][128 rows]
  int*   kbuf = reinterpret_cast<int*>(lds + 4096);     // [8][128]
  int*   ibuf = reinterpret_cast<int*>(lds + 8192);     // [128]
  if (l < 32) {
#pragma unroll
    for (int q = 0; q < 4; ++q) {
      fbuf[w * 128 + q * 32 + l] = gbest[q];
      kbuf[w * 128 + q * 32 + l] = bk[q];
    }
  }
  __syncthreads();

  if (tid < 128) {
    float bb = fbuf[tid];
    int   kk = kbuf[tid];
#pragma unroll
    for (int ww = 1; ww < 8; ++ww) {
      float b2 = fbuf[ww * 128 + tid];
      int   k2 = kbuf[ww * 128 + tid];
      if (b2 > bb || (b2 == bb && k2 < kk)) { bb = b2; kk = k2; }
    }
    ibuf[tid] = kk;
    out[NQ + 2 + rowbase + tid] = (float)kk;
  }
  __syncthreads();

  // --- gather + losses: 4 threads per row ---
  {
    const int row_l = tid >> 2, seg = tid & 3;
    const int idx  = ibuf[row_l];
    const int grow = rowbase + row_l;
    const float4* qp = reinterpret_cast<const float4*>(cb + (size_t)idx * D_DIM + seg * 16);
    const float4* zp = reinterpret_cast<const float4*>(z + (size_t)grow * D_DIM + seg * 16);
    float4*       op = reinterpret_cast<float4*>(out + (size_t)grow * D_DIM + seg * 16);
    float lp = 0.f;
#pragma unroll
    for (int cc = 0; cc < 4; ++cc) {
      float4 qv = qp[cc], zv = zp[cc];
      op[cc] = qv;
      float dx = zv.x - qv.x, dy = zv.y - qv.y;
      float dz = zv.z - qv.z, dw = zv.w - qv.w;
      lp += (dx * dx + dy * dy) + (dz * dz + dw * dw);
    }
#pragma unroll
    for (int off = 32; off > 0; off >>= 1) lp += __shfl_down(lp, off, 64);
    if (l == 0) atomicAdd(ws + WS_LOSS, lp);
  }
}

// ------------------------------------------------- fallback (R4-style; adapted
// to r2n semantics: score = r2n + dot, maximize)
__global__ __launch_bounds__(512, 2) void vq_main_reg(const float* __restrict__ z,
                                                      const float* __restrict__ cb,
                                                      float* __restrict__ ws,
                                                      float* __restrict__ out) {
  __shared__ __attribute__((aligned(16))) unsigned char lds[65536];
  const int tid = threadIdx.x;
  const int w = tid >> 6, l = tid & 63;
  const int rg = w >> 1, sp = w & 1;
  const int c = l & 31, g = l >> 5;
  const int rowbase = blockIdx.x * 128;
  const int myrow = rowbase + rg * 32 + c;

  bf16x8 zh[4], zl[4];
#pragma unroll
  for (int s = 0; s < 4; ++s) {
    const float* zp = z + (size_t)myrow * D_DIM + 16 * s + 8 * g;
    float4 f0 = *reinterpret_cast<const float4*>(zp);
    float4 f1 = *reinterpret_cast<const float4*>(zp + 4);
    float xs[8] = {f0.x, f0.y, f0.z, f0.w, f1.x, f1.y, f1.z, f1.w};
#pragma unroll
    for (int j = 0; j < 8; ++j) {
      __bf16 h = (__bf16)xs[j];
      zh[s][j] = h; zl[s][j] = (__bf16)(xs[j] - (float)h);
    }
  }
  const int st_t01 = tid >> 8;
  const int st_c   = (tid >> 3) & 31;
  const int st_ch  = tid & 7;
  const unsigned st_off = (unsigned)(st_t01 * 16384 + st_ch * 512 + st_c * 16);
  const float* st_g = cb + (size_t)(st_t01 * 32 + st_c) * D_DIM + st_ch * 8;

  float best = -FLT_MAX;
  int   bidx = 0;
  float4 p0 = *reinterpret_cast<const float4*>(st_g);
  float4 p1 = *reinterpret_cast<const float4*>(st_g + 4);
  {
    float xs[8] = {p0.x, p0.y, p0.z, p0.w, p1.x, p1.y, p1.z, p1.w};
    bf16x8 hi, lo;
#pragma unroll
    for (int j = 0; j < 8; ++j) {
      __bf16 h = (__bf16)xs[j];
      hi[j] = h; lo[j] = (__bf16)(xs[j] - (float)h);
    }
    *reinterpret_cast<bf16x8*>(lds + st_off)        = hi;
    *reinterpret_cast<bf16x8*>(lds + st_off + 8192) = lo;
  }
  __syncthreads();
  const unsigned rd_base = (unsigned)(sp * 16384 + c * 16);
  for (int r = 0; r < 128; ++r) {
    const int buf = r & 1;
    if (r < 127) {
      const float* gp = st_g + (size_t)(r + 1) * (64 * D_DIM);
      p0 = *reinterpret_cast<const float4*>(gp);
      p1 = *reinterpret_cast<const float4*>(gp + 4);
    }
    const unsigned b0 = (unsigned)buf * 32768u + rd_base;
    bf16x8 ch[4], cl[4];
#pragma unroll
    for (int s = 0; s < 4; ++s) {
      unsigned off = b0 + (unsigned)((2 * s + g) * 512);
      ch[s] = *reinterpret_cast<const bf16x8*>(lds + off);
      cl[s] = *reinterpret_cast<const bf16x8*>(lds + off + 8192);
    }
    f32x16 acc;
#pragma unroll
    for (int i = 0; i < 16; ++i) acc[i] = 0.f;
#pragma unroll
    for (int s = 0; s < 4; ++s) {
      acc = __builtin_amdgcn_mfma_f32_32x32x16_bf16(ch[s], zh[s], acc, 0, 0, 0);
      acc = __builtin_amdgcn_mfma_f32_32x32x16_bf16(ch[s], zl[s], acc, 0, 0, 0);
      acc = __builtin_amdgcn_mfma_f32_32x32x16_bf16(cl[s], zh[s], acc, 0, 0, 0);
    }
    const int tb = (2 * r + sp) * 32 + 4 * g;
#pragma unroll
    for (int q = 0; q < 4; ++q) {
      float4 rv = *reinterpret_cast<const float4*>(ws + tb + 8 * q);
      float ra[4] = {rv.x, rv.y, rv.z, rv.w};
#pragma unroll
      for (int j = 0; j < 4; ++j) {
        float sc = ra[j] + acc[4 * q + j];   // r2n + dot, maximize
        int kg = tb + 8 * q + j;
        if (sc > best) { best = sc; bidx = kg; }
      }
    }
    if (r < 127) {
      float xs[8] = {p0.x, p0.y, p0.z, p0.w, p1.x, p1.y, p1.z, p1.w};
      bf16x8 hi, lo;
#pragma unroll
      for (int j = 0; j < 8; ++j) {
        __bf16 h = (__bf16)xs[j];
        hi[j] = h; lo[j] = (__bf16)(xs[j] - (float)h);
      }
      unsigned wo = (unsigned)(buf ^ 1) * 32768u + st_off;
      *reinterpret_cast<bf16x8*>(lds + wo)        = hi;
      *reinterpret_cast<bf16x8*>(lds + wo + 8192) = lo;
    }
    __syncthreads();
  }
  {
    float ob = __shfl_xor(best, 32, 64);
    int   oi = __shfl_xor(bidx, 32, 64);
    if (ob > best || (ob == best && oi < bidx)) { best = ob; bidx = oi; }
  }
  float* mf  = reinterpret_cast<float*>(lds);
  int*   mi  = reinterpret_cast<int*>(lds + 1024);
  int*   mix = reinterpret_cast<int*>(lds + 2048);
  if (l < 32) { mf[w * 32 + c] = best; mi[w * 32 + c] = bidx; }
  __syncthreads();
  if (tid < 128) {
    int rgg = tid >> 5, rl = tid & 31;
    float b0 = mf[(2 * rgg) * 32 + rl];     int i0 = mi[(2 * rgg) * 32 + rl];
    float b1 = mf[(2 * rgg + 1) * 32 + rl]; int i1 = mi[(2 * rgg + 1) * 32 + rl];
    int idx = (b1 > b0 || (b1 == b0 && i1 < i0)) ? i1 : i0;
    mix[tid] = idx;
    out[NQ + 2 + rowbase + tid] = (float)idx;
  }
  __syncthreads();
  {
    const int row_l = tid >> 2, seg = tid & 3;
    const int idx  = mix[row_l];
    const int grow = rowbase + row_l;
    const float4* qp = reinterpret_cast<const float4*>(cb + (size_t)idx * D_DIM + seg * 16);
    const float4* zp = reinterpret_cast<const float4*>(z + (size_t)grow * D_DIM + seg * 16);
    float4*       op = reinterpret_cast<float4*>(out + (size_t)grow * D_DIM + seg * 16);
    float lp = 0.f;
#pragma unroll
    for (int cc = 0; cc < 4; ++cc) {
      float4 qv = qp[cc], zv = zp[cc];
      op[cc] = qv;
      float dx = zv.x - qv.x, dy = zv.y - qv.y;
      float dz = zv.z - qv.z, dw = zv.w - qv.w;
      lp += (dx * dx + dy * dy) + (dz * dz + dw * dw);
    }
#pragma unroll
    for (int off = 32; off > 0; off >>= 1) lp += __shfl_down(lp, off, 64);
    if (l == 0) atomicAdd(ws + WS_LOSS, lp);
  }
}

// ------------------------------------------------------------ finalize kernel
__global__ void vq_fin(const float* __restrict__ ws, float* __restrict__ out) {
  float mm = ws[WS_LOSS] * (1.0f / (float)(N_ROWS * D_DIM));
  out[NQ]     = mm;
  out[NQ + 1] = mm;
}

// -------------------------------------------------------------------- launch
extern "C" void kernel_launch(void* const* d_in, const int* in_sizes, int n_in,
                              void* d_out, int out_size, void* d_ws, size_t ws_size,
                              hipStream_t stream) {
  (void)in_sizes; (void)n_in; (void)out_size;
  const float* z  = (const float*)d_in[0];
  const float* cb = (const float*)d_in[1];
  float* out = (float*)d_out;
  float* ws  = (float*)d_ws;

  vq_prep<<<K_CB / 256, 256, 0, stream>>>(cb, ws);
  if (ws_size >= WS_NEED) {
    vq_split<<<256, 256, 0, stream>>>(cb, ws);
    vq_dm<<<N_ROWS / 128, 512, 0, stream>>>(z, cb, ws, out);
  } else {
    vq_main_reg<<<N_ROWS / 128, 512, 0, stream>>>(z, cb, ws, out);
  }
  vq_fin<<<1, 1, 0, stream>>>(ws, out);
}